// Round 1
// baseline (907.131 us; speedup 1.0000x reference)
//
#include <hip/hip_runtime.h>

#define D 128
#define TM 32

// ---------------- CSR build ----------------

__global__ void zero_i32(int* __restrict__ p, int n) {
    int i = blockIdx.x * blockDim.x + threadIdx.x;
    if (i < n) p[i] = 0;
}

__global__ void count_deg(const int* __restrict__ coli, int* __restrict__ deg, int e) {
    int i = blockIdx.x * blockDim.x + threadIdx.x;
    if (i < e) atomicAdd(&deg[coli[i]], 1);
}

// per-block exclusive scan (256 elems/block); block sums to bsum
__global__ void scan1(const int* __restrict__ deg, int* __restrict__ row_ptr,
                      int* __restrict__ bsum, int n) {
    __shared__ int s[256];
    int t = threadIdx.x;
    int i = blockIdx.x * 256 + t;
    int v = (i < n) ? deg[i] : 0;
    s[t] = v;
    __syncthreads();
    #pragma unroll
    for (int off = 1; off < 256; off <<= 1) {
        int add = (t >= off) ? s[t - off] : 0;
        __syncthreads();
        s[t] += add;
        __syncthreads();
    }
    if (i < n) row_ptr[i] = s[t] - v;          // exclusive within block
    if (t == 255) bsum[blockIdx.x] = s[255];
}

// scan the (<=512) block sums in one block -> exclusive
__global__ void scan2(int* __restrict__ bsum, int nb) {
    __shared__ int s[512];
    int t = threadIdx.x;
    int v = (t < nb) ? bsum[t] : 0;
    s[t] = v;
    __syncthreads();
    #pragma unroll
    for (int off = 1; off < 512; off <<= 1) {
        int add = (t >= off) ? s[t - off] : 0;
        __syncthreads();
        s[t] += add;
        __syncthreads();
    }
    if (t < nb) bsum[t] = s[t] - v;            // exclusive
}

__global__ void scan3(int* __restrict__ row_ptr, int* __restrict__ cursor,
                      const int* __restrict__ bsum, int n, int e) {
    int i = blockIdx.x * blockDim.x + threadIdx.x;
    if (i < n) {
        int v = row_ptr[i] + bsum[i >> 8];
        row_ptr[i] = v;
        cursor[i] = v;
    } else if (i == n) {
        row_ptr[n] = e;
    }
}

__global__ void scatter_edges(const int* __restrict__ rowi, const int* __restrict__ coli,
                              int* __restrict__ cursor, int* __restrict__ srcs, int e) {
    int i = blockIdx.x * blockDim.x + threadIdx.x;
    if (i < e) {
        int pos = atomicAdd(&cursor[coli[i]], 1);
        srcs[pos] = rowi[i];
    }
}

// ---------------- mean aggregation: one wave per node ----------------
// lane d handles dims 2d, 2d+1 -> one 512B coalesced read per neighbor.
__global__ __launch_bounds__(256) void aggregate_mean(
    const float* __restrict__ x, float* __restrict__ mean,
    const int* __restrict__ row_ptr, const int* __restrict__ srcs, int n) {
    int node = blockIdx.x * 4 + (threadIdx.x >> 6);
    if (node >= n) return;
    int lane = threadIdx.x & 63;
    int beg = row_ptr[node];
    int end = row_ptr[node + 1];
    float ax = 0.f, ay = 0.f;
    for (int j = beg; j < end; ++j) {
        int s = srcs[j];  // wave-uniform -> scalar load
        float2 v = *reinterpret_cast<const float2*>(x + (size_t)s * D + lane * 2);
        ax += v.x;
        ay += v.y;
    }
    float inv = 1.0f / fmaxf((float)(end - beg), 1.0f);
    float2 o;
    o.x = ax * inv;
    o.y = ay * inv;
    *reinterpret_cast<float2*>(mean + (size_t)node * D + lane * 2) = o;
}

// ---------------- fused dual-GEMM + bias + relu ----------------
// out[r][d] = relu( sum_k agg[r][k]*wl[k][d] + bias[d] + sum_k xin[r][k]*wr[k][d] )
// 32-row tile in LDS; thread (d = tid&127, half = tid>>7) computes 16 rows, col d.
// LDS reads are wave-uniform (broadcast, conflict-free); weight loads coalesced.
__global__ __launch_bounds__(256) void sage_mm(
    const float* __restrict__ agg, const float* __restrict__ xin,
    const float* __restrict__ wl, const float* __restrict__ bias,
    const float* __restrict__ wr, float* __restrict__ out, int n) {
    __shared__ float sm[TM * D];
    __shared__ float sx[TM * D];
    const int tid = threadIdx.x;
    const size_t row0 = (size_t)blockIdx.x * TM;
    if (row0 >= (size_t)n) return;

    const float4* gm = reinterpret_cast<const float4*>(agg + row0 * D);
    const float4* gx = reinterpret_cast<const float4*>(xin + row0 * D);
    float4* s4m = reinterpret_cast<float4*>(sm);
    float4* s4x = reinterpret_cast<float4*>(sx);
    #pragma unroll
    for (int i = 0; i < (TM * D / 4) / 256; ++i) {  // 4 iters
        s4m[tid + i * 256] = gm[tid + i * 256];
        s4x[tid + i * 256] = gx[tid + i * 256];
    }
    __syncthreads();

    const int d_ = tid & 127;
    const int rbase = (tid >> 7) * (TM / 2);
    const float b = bias[d_];
    float acc[TM / 2];
    #pragma unroll
    for (int r = 0; r < TM / 2; ++r) acc[r] = b;

    for (int k4 = 0; k4 < D / 4; ++k4) {
        float wlv[4], wrv[4];
        #pragma unroll
        for (int j = 0; j < 4; ++j) {
            wlv[j] = wl[(k4 * 4 + j) * D + d_];
            wrv[j] = wr[(k4 * 4 + j) * D + d_];
        }
        #pragma unroll
        for (int r = 0; r < TM / 2; ++r) {
            float4 m = reinterpret_cast<const float4*>(sm + (rbase + r) * D)[k4];
            float4 xv = reinterpret_cast<const float4*>(sx + (rbase + r) * D)[k4];
            acc[r] += m.x * wlv[0] + m.y * wlv[1] + m.z * wlv[2] + m.w * wlv[3]
                    + xv.x * wrv[0] + xv.y * wrv[1] + xv.z * wrv[2] + xv.w * wrv[3];
        }
    }

    #pragma unroll
    for (int r = 0; r < TM / 2; ++r) {
        out[(row0 + rbase + r) * D + d_] = fmaxf(acc[r], 0.0f);
    }
}

// ---------------- launch ----------------

extern "C" void kernel_launch(void* const* d_in, const int* in_sizes, int n_in,
                              void* d_out, int out_size, void* d_ws, size_t ws_size,
                              hipStream_t stream) {
    const float* x   = (const float*)d_in[0];
    const int*   ei  = (const int*)d_in[1];
    const float* w1l = (const float*)d_in[2];
    const float* b1l = (const float*)d_in[3];
    const float* w1r = (const float*)d_in[4];
    const float* w2l = (const float*)d_in[5];
    const float* b2l = (const float*)d_in[6];
    const float* w2r = (const float*)d_in[7];
    float* out = (float*)d_out;

    const int n = in_sizes[0] / D;   // 100000
    const int e = in_sizes[1] / 2;   // 1600000
    const int* rowi = ei;            // sources
    const int* coli = ei + e;        // targets

    // workspace layout (ints), 256B-aligned chunks
    const int PN = ((n + 1 + 63) / 64) * 64;   // 100096
    int* ws_i     = (int*)d_ws;
    int* row_ptr  = ws_i;                       // PN
    int* cursor   = row_ptr + PN;               // PN
    int* deg      = cursor + PN;                // PN
    int* bsum     = deg + PN;                   // 512
    int* srcs     = bsum + 512;                 // e
    float* mean   = (float*)(srcs + e);         // n*D floats

    const int nb = (n + 255) / 256;             // 391 (<=512 required by scan2)

    zero_i32<<<(n + 255) / 256, 256, 0, stream>>>(deg, n);
    count_deg<<<(e + 255) / 256, 256, 0, stream>>>(coli, deg, e);
    scan1<<<nb, 256, 0, stream>>>(deg, row_ptr, bsum, n);
    scan2<<<1, 512, 0, stream>>>(bsum, nb);
    scan3<<<(n + 1 + 255) / 256, 256, 0, stream>>>(row_ptr, cursor, bsum, n, e);
    scatter_edges<<<(e + 255) / 256, 256, 0, stream>>>(rowi, coli, cursor, srcs, e);

    // layer 1: h = relu(mean(x)@w1l + b1l + x@w1r), h stored in d_out
    aggregate_mean<<<(n + 3) / 4, 256, 0, stream>>>(x, mean, row_ptr, srcs, n);
    sage_mm<<<n / TM, 256, 0, stream>>>(mean, x, w1l, b1l, w1r, out, n);

    // layer 2: out = relu(mean(h)@w2l + b2l + h@w2r), in place over h
    aggregate_mean<<<(n + 3) / 4, 256, 0, stream>>>(out, mean, row_ptr, srcs, n);
    sage_mm<<<n / TM, 256, 0, stream>>>(mean, out, w2l, b2l, w2r, out, n);
}

// Round 3
// 715.096 us; speedup vs baseline: 1.2685x; 1.2685x over previous
//
#include <hip/hip_runtime.h>

#define D 128
#define BM 128
#define KC 32
#define LDA 36   // KC + 4 pad (keeps float4 alignment, shifts banks per row)
#define LDB 132  // D + 4 pad

// ---------------- CSR build ----------------

__global__ void zero_i32(int* __restrict__ p, int n) {
    int i = blockIdx.x * blockDim.x + threadIdx.x;
    if (i < n) p[i] = 0;
}

__global__ void count_deg(const int* __restrict__ coli, int* __restrict__ deg, int e) {
    int i = blockIdx.x * blockDim.x + threadIdx.x;
    if (i < e) atomicAdd(&deg[coli[i]], 1);
}

__global__ void scan1(const int* __restrict__ deg, int* __restrict__ row_ptr,
                      int* __restrict__ bsum, int n) {
    __shared__ int s[256];
    int t = threadIdx.x;
    int i = blockIdx.x * 256 + t;
    int v = (i < n) ? deg[i] : 0;
    s[t] = v;
    __syncthreads();
    #pragma unroll
    for (int off = 1; off < 256; off <<= 1) {
        int add = (t >= off) ? s[t - off] : 0;
        __syncthreads();
        s[t] += add;
        __syncthreads();
    }
    if (i < n) row_ptr[i] = s[t] - v;
    if (t == 255) bsum[blockIdx.x] = s[255];
}

__global__ void scan2(int* __restrict__ bsum, int nb) {
    __shared__ int s[512];
    int t = threadIdx.x;
    int v = (t < nb) ? bsum[t] : 0;
    s[t] = v;
    __syncthreads();
    #pragma unroll
    for (int off = 1; off < 512; off <<= 1) {
        int add = (t >= off) ? s[t - off] : 0;
        __syncthreads();
        s[t] += add;
        __syncthreads();
    }
    if (t < nb) bsum[t] = s[t] - v;
}

__global__ void scan3(int* __restrict__ row_ptr, int* __restrict__ cursor,
                      const int* __restrict__ bsum, int n, int e) {
    int i = blockIdx.x * blockDim.x + threadIdx.x;
    if (i < n) {
        int v = row_ptr[i] + bsum[i >> 8];
        row_ptr[i] = v;
        cursor[i] = v;
    } else if (i == n) {
        row_ptr[n] = e;
    }
}

__global__ void scatter_edges(const int* __restrict__ rowi, const int* __restrict__ coli,
                              int* __restrict__ cursor, int* __restrict__ srcs, int e) {
    int i = blockIdx.x * blockDim.x + threadIdx.x;
    if (i < e) {
        int pos = atomicAdd(&cursor[coli[i]], 1);
        srcs[pos] = rowi[i];
    }
}

// ---------------- mean aggregation ----------------
// one wave per node; 32 lanes x float4 cover one 512B row -> 2 neighbors/iter,
// unrolled x2 -> 4 neighbors (2KB) in flight.
__global__ __launch_bounds__(256) void aggregate_mean(
    const float* __restrict__ x, float* __restrict__ mean,
    const int* __restrict__ row_ptr, const int* __restrict__ srcs, int n) {
    int node = blockIdx.x * 4 + (threadIdx.x >> 6);
    if (node >= n) return;
    int lane = threadIdx.x & 63;
    int half = lane >> 5;
    int l32 = lane & 31;
    int beg = row_ptr[node];
    int end = row_ptr[node + 1];

    float4 a0 = make_float4(0.f, 0.f, 0.f, 0.f);
    float4 a1 = make_float4(0.f, 0.f, 0.f, 0.f);
    int j = beg;
    for (; j + 4 <= end; j += 4) {
        int s0 = srcs[j + half];
        int s1 = srcs[j + 2 + half];
        float4 v0 = *reinterpret_cast<const float4*>(x + (size_t)s0 * D + l32 * 4);
        float4 v1 = *reinterpret_cast<const float4*>(x + (size_t)s1 * D + l32 * 4);
        a0.x += v0.x; a0.y += v0.y; a0.z += v0.z; a0.w += v0.w;
        a1.x += v1.x; a1.y += v1.y; a1.z += v1.z; a1.w += v1.w;
    }
    if (j + 2 <= end) {
        int s0 = srcs[j + half];
        float4 v0 = *reinterpret_cast<const float4*>(x + (size_t)s0 * D + l32 * 4);
        a0.x += v0.x; a0.y += v0.y; a0.z += v0.z; a0.w += v0.w;
        j += 2;
    }
    if (j < end && half == 0) {
        int s0 = srcs[j];
        float4 v0 = *reinterpret_cast<const float4*>(x + (size_t)s0 * D + l32 * 4);
        a0.x += v0.x; a0.y += v0.y; a0.z += v0.z; a0.w += v0.w;
    }
    a0.x += a1.x; a0.y += a1.y; a0.z += a1.z; a0.w += a1.w;
    // combine the two halves (lane ^ 32)
    a0.x += __shfl_xor(a0.x, 32, 64);
    a0.y += __shfl_xor(a0.y, 32, 64);
    a0.z += __shfl_xor(a0.z, 32, 64);
    a0.w += __shfl_xor(a0.w, 32, 64);

    if (half == 0) {
        float inv = 1.0f / fmaxf((float)(end - beg), 1.0f);
        float4 o;
        o.x = a0.x * inv; o.y = a0.y * inv; o.z = a0.z * inv; o.w = a0.w * inv;
        *reinterpret_cast<float4*>(mean + (size_t)node * D + l32 * 4) = o;
    }
}

// ---------------- fused dual-GEMM + bias + relu ----------------
// out = relu([mean | xin] @ [wl ; wr] + bias): one K=256 GEMM.
// Block: 128 rows x 128 cols, 256 threads, 8x8 register tile each.
// K staged in 8 chunks of 32 (A: 18KB, B: 17KB LDS).
__device__ inline void fma4(float4& d, float a, const float4& b) {
    d.x += a * b.x; d.y += a * b.y; d.z += a * b.z; d.w += a * b.w;
}

__global__ __launch_bounds__(256, 2) void sage_mm(
    const float* __restrict__ mean, const float* __restrict__ xin,
    const float* __restrict__ wl, const float* __restrict__ bias,
    const float* __restrict__ wr, float* __restrict__ out, int n) {
    __shared__ float smA[BM * LDA];
    __shared__ float smB[KC * LDB];
    const int tid = threadIdx.x;
    const int row0 = blockIdx.x * BM;
    const int tc = tid & 15;
    const int tr = tid >> 4;

    float4 acc[8][2];
    {
        float4 b0 = *reinterpret_cast<const float4*>(&bias[tc * 8]);
        float4 b1 = *reinterpret_cast<const float4*>(&bias[tc * 8 + 4]);
        #pragma unroll
        for (int ri = 0; ri < 8; ++ri) { acc[ri][0] = b0; acc[ri][1] = b1; }
    }

    for (int c = 0; c < 8; ++c) {
        const float* __restrict__ asrc = (c < 4) ? mean : xin;
        const float* __restrict__ bsrc = (c < 4) ? wl : wr;
        const int k0 = (c & 3) * KC;
        // stage A chunk [128 rows][32 k]
        #pragma unroll
        for (int i = 0; i < 4; ++i) {
            int f = tid + i * 256;
            int row = f >> 3, kq = f & 7;
            int gr = row0 + row;
            float4 v = make_float4(0.f, 0.f, 0.f, 0.f);
            if (gr < n)
                v = *reinterpret_cast<const float4*>(&asrc[(size_t)gr * D + k0 + kq * 4]);
            *reinterpret_cast<float4*>(&smA[row * LDA + kq * 4]) = v;
        }
        // stage B chunk [32 k][128 c]
        #pragma unroll
        for (int i = 0; i < 4; ++i) {
            int f = tid + i * 256;
            int bk = f >> 5, c4 = f & 31;
            *reinterpret_cast<float4*>(&smB[bk * LDB + c4 * 4]) =
                *reinterpret_cast<const float4*>(&bsrc[(size_t)(k0 + bk) * D + c4 * 4]);
        }
        __syncthreads();
        #pragma unroll
        for (int kq = 0; kq < 8; ++kq) {
            float4 af[8];
            float4 bf[4][2];
            #pragma unroll
            for (int ri = 0; ri < 8; ++ri)
                af[ri] = *reinterpret_cast<const float4*>(&smA[(tr * 8 + ri) * LDA + kq * 4]);
            #pragma unroll
            for (int kk = 0; kk < 4; ++kk) {
                bf[kk][0] = *reinterpret_cast<const float4*>(&smB[(kq * 4 + kk) * LDB + tc * 8]);
                bf[kk][1] = *reinterpret_cast<const float4*>(&smB[(kq * 4 + kk) * LDB + tc * 8 + 4]);
            }
            #pragma unroll
            for (int ri = 0; ri < 8; ++ri) {
                fma4(acc[ri][0], af[ri].x, bf[0][0]); fma4(acc[ri][1], af[ri].x, bf[0][1]);
                fma4(acc[ri][0], af[ri].y, bf[1][0]); fma4(acc[ri][1], af[ri].y, bf[1][1]);
                fma4(acc[ri][0], af[ri].z, bf[2][0]); fma4(acc[ri][1], af[ri].z, bf[2][1]);
                fma4(acc[ri][0], af[ri].w, bf[3][0]); fma4(acc[ri][1], af[ri].w, bf[3][1]);
            }
        }
        __syncthreads();
    }

    #pragma unroll
    for (int ri = 0; ri < 8; ++ri) {
        int gr = row0 + tr * 8 + ri;
        if (gr < n) {
            float4 o0 = acc[ri][0], o1 = acc[ri][1];
            o0.x = fmaxf(o0.x, 0.f); o0.y = fmaxf(o0.y, 0.f);
            o0.z = fmaxf(o0.z, 0.f); o0.w = fmaxf(o0.w, 0.f);
            o1.x = fmaxf(o1.x, 0.f); o1.y = fmaxf(o1.y, 0.f);
            o1.z = fmaxf(o1.z, 0.f); o1.w = fmaxf(o1.w, 0.f);
            *reinterpret_cast<float4*>(&out[(size_t)gr * D + tc * 8]) = o0;
            *reinterpret_cast<float4*>(&out[(size_t)gr * D + tc * 8 + 4]) = o1;
        }
    }
}

// ---------------- launch ----------------

extern "C" void kernel_launch(void* const* d_in, const int* in_sizes, int n_in,
                              void* d_out, int out_size, void* d_ws, size_t ws_size,
                              hipStream_t stream) {
    const float* x   = (const float*)d_in[0];
    const int*   ei  = (const int*)d_in[1];
    const float* w1l = (const float*)d_in[2];
    const float* b1l = (const float*)d_in[3];
    const float* w1r = (const float*)d_in[4];
    const float* w2l = (const float*)d_in[5];
    const float* b2l = (const float*)d_in[6];
    const float* w2r = (const float*)d_in[7];
    float* out = (float*)d_out;

    const int n = in_sizes[0] / D;   // 100000
    const int e = in_sizes[1] / 2;   // 1600000
    const int* rowi = ei;            // sources
    const int* coli = ei + e;        // targets

    const int PN = ((n + 1 + 63) / 64) * 64;
    int* ws_i     = (int*)d_ws;
    int* row_ptr  = ws_i;
    int* cursor   = row_ptr + PN;
    int* deg      = cursor + PN;
    int* bsum     = deg + PN;
    int* srcs     = bsum + 512;
    float* mean   = (float*)(srcs + e);

    const int nb = (n + 255) / 256;

    zero_i32<<<(n + 255) / 256, 256, 0, stream>>>(deg, n);
    count_deg<<<(e + 255) / 256, 256, 0, stream>>>(coli, deg, e);
    scan1<<<nb, 256, 0, stream>>>(deg, row_ptr, bsum, n);
    scan2<<<1, 512, 0, stream>>>(bsum, nb);
    scan3<<<(n + 1 + 255) / 256, 256, 0, stream>>>(row_ptr, cursor, bsum, n, e);
    scatter_edges<<<(e + 255) / 256, 256, 0, stream>>>(rowi, coli, cursor, srcs, e);

    const int mm_grid = (n + BM - 1) / BM;

    // layer 1: h = relu(mean(x)@w1l + b1l + x@w1r), h in d_out
    aggregate_mean<<<(n + 3) / 4, 256, 0, stream>>>(x, mean, row_ptr, srcs, n);
    sage_mm<<<mm_grid, 256, 0, stream>>>(mean, x, w1l, b1l, w1r, out, n);

    // layer 2: out = relu(mean(h)@w2l + b2l + h@w2r), in place over h
    aggregate_mean<<<(n + 3) / 4, 256, 0, stream>>>(out, mean, row_ptr, srcs, n);
    sage_mm<<<mm_grid, 256, 0, stream>>>(mean, out, w2l, b2l, w2r, out, n);
}

// Round 4
// 583.497 us; speedup vs baseline: 1.5546x; 1.2255x over previous
//
#include <hip/hip_runtime.h>

#define D 128
#define BM 128
#define KC 32
#define LDA 36   // KC + 4 pad
#define LDB 132  // D + 4 pad
#define NWG 256  // workgroups in hist/scatter phases

// ---------------- generic scan (256/block) ----------------

__global__ void scan1(const int* __restrict__ in, int* __restrict__ out,
                      int* __restrict__ bsum, int n) {
    __shared__ int s[256];
    int t = threadIdx.x;
    int i = blockIdx.x * 256 + t;
    int v = (i < n) ? in[i] : 0;
    s[t] = v;
    __syncthreads();
    #pragma unroll
    for (int off = 1; off < 256; off <<= 1) {
        int add = (t >= off) ? s[t - off] : 0;
        __syncthreads();
        s[t] += add;
        __syncthreads();
    }
    if (i < n) out[i] = s[t] - v;          // exclusive within block
    if (t == 255) bsum[blockIdx.x] = s[255];
}

__global__ void scan2(int* __restrict__ bsum, int nb) {
    __shared__ int s[512];
    int t = threadIdx.x;
    int v = (t < nb) ? bsum[t] : 0;
    s[t] = v;
    __syncthreads();
    #pragma unroll
    for (int off = 1; off < 512; off <<= 1) {
        int add = (t >= off) ? s[t - off] : 0;
        __syncthreads();
        s[t] += add;
        __syncthreads();
    }
    if (t < nb) bsum[t] = s[t] - v;        // exclusive
}

__global__ void scan3b(int* __restrict__ out, const int* __restrict__ bsum, int n) {
    int i = blockIdx.x * blockDim.x + threadIdx.x;
    if (i < n) out[i] += bsum[i >> 8];
}

__global__ void set_end(int* __restrict__ row_ptr, int n, int e) {
    row_ptr[n] = e;
}

// ---------------- phase A: bucket histogram + scatter ----------------
// bucket b = col >> 8 (256 nodes per bucket), nbkt <= 512.

__global__ __launch_bounds__(256) void hist_bucket(const int* __restrict__ coli,
                                                   int* __restrict__ hist_t,
                                                   int e, int nbkt, int cpw) {
    __shared__ int hist[512];
    int w = blockIdx.x, tid = threadIdx.x;
    for (int b = tid; b < nbkt; b += 256) hist[b] = 0;
    __syncthreads();
    int i1 = min((w + 1) * cpw, e);
    for (int i = w * cpw + tid; i < i1; i += 256)
        atomicAdd(&hist[coli[i] >> 8], 1);
    __syncthreads();
    for (int b = tid; b < nbkt; b += 256) hist_t[b * NWG + w] = hist[b];
}

__global__ __launch_bounds__(256) void scatter_bucket(const int* __restrict__ rowi,
                                                      const int* __restrict__ coli,
                                                      const int* __restrict__ scanned,
                                                      unsigned int* __restrict__ ebuf,
                                                      int e, int nbkt, int cpw) {
    __shared__ int cur[512];
    int w = blockIdx.x, tid = threadIdx.x;
    for (int b = tid; b < nbkt; b += 256) cur[b] = scanned[b * NWG + w];
    __syncthreads();
    int i1 = min((w + 1) * cpw, e);
    for (int i = w * cpw + tid; i < i1; i += 256) {
        int c = coli[i];
        int b = c >> 8;
        int p = atomicAdd(&cur[b], 1);
        ebuf[p] = ((unsigned int)rowi[i] << 8) | (unsigned int)(c & 255);
    }
}

// ---------------- phase B: per-bucket local CSR ----------------
__global__ __launch_bounds__(256) void csr_bucket(const int* __restrict__ scanned,
                                                  const unsigned int* __restrict__ ebuf,
                                                  int* __restrict__ row_ptr,
                                                  int* __restrict__ srcs,
                                                  int e, int n, int nbkt) {
    __shared__ int cnt[256], s[256], cur[256];
    int b = blockIdx.x, tid = threadIdx.x;
    int S = scanned[b * NWG];
    int Send = (b == nbkt - 1) ? e : scanned[(b + 1) * NWG];
    cnt[tid] = 0;
    __syncthreads();
    for (int i = S + tid; i < Send; i += 256)
        atomicAdd(&cnt[ebuf[i] & 255], 1);
    __syncthreads();
    int v = cnt[tid];
    s[tid] = v;
    __syncthreads();
    #pragma unroll
    for (int off = 1; off < 256; off <<= 1) {
        int add = (tid >= off) ? s[tid - off] : 0;
        __syncthreads();
        s[tid] += add;
        __syncthreads();
    }
    int offx = s[tid] - v;                 // exclusive local offset
    int node = b * 256 + tid;
    if (node < n) row_ptr[node] = S + offx;
    cur[tid] = offx;
    __syncthreads();
    for (int i = S + tid; i < Send; i += 256) {
        unsigned int pe = ebuf[i];
        int lc = (int)(pe & 255u);
        int p = S + atomicAdd(&cur[lc], 1);
        srcs[p] = (int)(pe >> 8);
    }
}

// ---------------- mean aggregation ----------------
// one wave per node; 32 lanes x float4 = one 512B row; half-waves pair up ->
// 8 neighbors (4KB) outstanding per iteration.
__global__ __launch_bounds__(256) void aggregate_mean(
    const float* __restrict__ x, float* __restrict__ mean,
    const int* __restrict__ row_ptr, const int* __restrict__ srcs, int n) {
    int node = blockIdx.x * 4 + (threadIdx.x >> 6);
    if (node >= n) return;
    int lane = threadIdx.x & 63;
    int half = lane >> 5;
    int l32 = lane & 31;
    int beg = row_ptr[node];
    int end = row_ptr[node + 1];

    float4 a0 = make_float4(0.f, 0.f, 0.f, 0.f);
    float4 a1 = make_float4(0.f, 0.f, 0.f, 0.f);
    float4 a2 = make_float4(0.f, 0.f, 0.f, 0.f);
    float4 a3 = make_float4(0.f, 0.f, 0.f, 0.f);
    int j = beg;
    for (; j + 8 <= end; j += 8) {
        int s0 = srcs[j + half];
        int s1 = srcs[j + 2 + half];
        int s2 = srcs[j + 4 + half];
        int s3 = srcs[j + 6 + half];
        float4 v0 = *reinterpret_cast<const float4*>(x + (size_t)s0 * D + l32 * 4);
        float4 v1 = *reinterpret_cast<const float4*>(x + (size_t)s1 * D + l32 * 4);
        float4 v2 = *reinterpret_cast<const float4*>(x + (size_t)s2 * D + l32 * 4);
        float4 v3 = *reinterpret_cast<const float4*>(x + (size_t)s3 * D + l32 * 4);
        a0.x += v0.x; a0.y += v0.y; a0.z += v0.z; a0.w += v0.w;
        a1.x += v1.x; a1.y += v1.y; a1.z += v1.z; a1.w += v1.w;
        a2.x += v2.x; a2.y += v2.y; a2.z += v2.z; a2.w += v2.w;
        a3.x += v3.x; a3.y += v3.y; a3.z += v3.z; a3.w += v3.w;
    }
    if (j + 4 <= end) {
        int s0 = srcs[j + half];
        int s1 = srcs[j + 2 + half];
        float4 v0 = *reinterpret_cast<const float4*>(x + (size_t)s0 * D + l32 * 4);
        float4 v1 = *reinterpret_cast<const float4*>(x + (size_t)s1 * D + l32 * 4);
        a0.x += v0.x; a0.y += v0.y; a0.z += v0.z; a0.w += v0.w;
        a1.x += v1.x; a1.y += v1.y; a1.z += v1.z; a1.w += v1.w;
        j += 4;
    }
    if (j + 2 <= end) {
        int s0 = srcs[j + half];
        float4 v0 = *reinterpret_cast<const float4*>(x + (size_t)s0 * D + l32 * 4);
        a0.x += v0.x; a0.y += v0.y; a0.z += v0.z; a0.w += v0.w;
        j += 2;
    }
    if (j < end && half == 0) {
        int s0 = srcs[j];
        float4 v0 = *reinterpret_cast<const float4*>(x + (size_t)s0 * D + l32 * 4);
        a0.x += v0.x; a0.y += v0.y; a0.z += v0.z; a0.w += v0.w;
    }
    a0.x += a1.x + a2.x + a3.x;
    a0.y += a1.y + a2.y + a3.y;
    a0.z += a1.z + a2.z + a3.z;
    a0.w += a1.w + a2.w + a3.w;
    a0.x += __shfl_xor(a0.x, 32, 64);
    a0.y += __shfl_xor(a0.y, 32, 64);
    a0.z += __shfl_xor(a0.z, 32, 64);
    a0.w += __shfl_xor(a0.w, 32, 64);

    if (half == 0) {
        float inv = 1.0f / fmaxf((float)(end - beg), 1.0f);
        float4 o;
        o.x = a0.x * inv; o.y = a0.y * inv; o.z = a0.z * inv; o.w = a0.w * inv;
        *reinterpret_cast<float4*>(mean + (size_t)node * D + l32 * 4) = o;
    }
}

// ---------------- fused dual-GEMM + bias + relu ----------------
__device__ inline void fma4(float4& d, float a, const float4& b) {
    d.x += a * b.x; d.y += a * b.y; d.z += a * b.z; d.w += a * b.w;
}

__global__ __launch_bounds__(256, 2) void sage_mm(
    const float* __restrict__ mean, const float* __restrict__ xin,
    const float* __restrict__ wl, const float* __restrict__ bias,
    const float* __restrict__ wr, float* __restrict__ out, int n) {
    __shared__ float smA[BM * LDA];
    __shared__ float smB[KC * LDB];
    const int tid = threadIdx.x;
    const int row0 = blockIdx.x * BM;
    const int tc = tid & 15;
    const int tr = tid >> 4;

    float4 acc[8][2];
    {
        float4 b0 = *reinterpret_cast<const float4*>(&bias[tc * 8]);
        float4 b1 = *reinterpret_cast<const float4*>(&bias[tc * 8 + 4]);
        #pragma unroll
        for (int ri = 0; ri < 8; ++ri) { acc[ri][0] = b0; acc[ri][1] = b1; }
    }

    for (int c = 0; c < 8; ++c) {
        const float* __restrict__ asrc = (c < 4) ? mean : xin;
        const float* __restrict__ bsrc = (c < 4) ? wl : wr;
        const int k0 = (c & 3) * KC;
        #pragma unroll
        for (int i = 0; i < 4; ++i) {
            int f = tid + i * 256;
            int row = f >> 3, kq = f & 7;
            int gr = row0 + row;
            float4 v = make_float4(0.f, 0.f, 0.f, 0.f);
            if (gr < n)
                v = *reinterpret_cast<const float4*>(&asrc[(size_t)gr * D + k0 + kq * 4]);
            *reinterpret_cast<float4*>(&smA[row * LDA + kq * 4]) = v;
        }
        #pragma unroll
        for (int i = 0; i < 4; ++i) {
            int f = tid + i * 256;
            int bk = f >> 5, c4 = f & 31;
            *reinterpret_cast<float4*>(&smB[bk * LDB + c4 * 4]) =
                *reinterpret_cast<const float4*>(&bsrc[(size_t)(k0 + bk) * D + c4 * 4]);
        }
        __syncthreads();
        #pragma unroll
        for (int kq = 0; kq < 8; ++kq) {
            float4 af[8];
            float4 bf[4][2];
            #pragma unroll
            for (int ri = 0; ri < 8; ++ri)
                af[ri] = *reinterpret_cast<const float4*>(&smA[(tr * 8 + ri) * LDA + kq * 4]);
            #pragma unroll
            for (int kk = 0; kk < 4; ++kk) {
                bf[kk][0] = *reinterpret_cast<const float4*>(&smB[(kq * 4 + kk) * LDB + tc * 8]);
                bf[kk][1] = *reinterpret_cast<const float4*>(&smB[(kq * 4 + kk) * LDB + tc * 8 + 4]);
            }
            #pragma unroll
            for (int ri = 0; ri < 8; ++ri) {
                fma4(acc[ri][0], af[ri].x, bf[0][0]); fma4(acc[ri][1], af[ri].x, bf[0][1]);
                fma4(acc[ri][0], af[ri].y, bf[1][0]); fma4(acc[ri][1], af[ri].y, bf[1][1]);
                fma4(acc[ri][0], af[ri].z, bf[2][0]); fma4(acc[ri][1], af[ri].z, bf[2][1]);
                fma4(acc[ri][0], af[ri].w, bf[3][0]); fma4(acc[ri][1], af[ri].w, bf[3][1]);
            }
        }
        __syncthreads();
    }

    #pragma unroll
    for (int ri = 0; ri < 8; ++ri) {
        int gr = row0 + tr * 8 + ri;
        if (gr < n) {
            float4 o0 = acc[ri][0], o1 = acc[ri][1];
            o0.x = fmaxf(o0.x, 0.f); o0.y = fmaxf(o0.y, 0.f);
            o0.z = fmaxf(o0.z, 0.f); o0.w = fmaxf(o0.w, 0.f);
            o1.x = fmaxf(o1.x, 0.f); o1.y = fmaxf(o1.y, 0.f);
            o1.z = fmaxf(o1.z, 0.f); o1.w = fmaxf(o1.w, 0.f);
            *reinterpret_cast<float4*>(&out[(size_t)gr * D + tc * 8]) = o0;
            *reinterpret_cast<float4*>(&out[(size_t)gr * D + tc * 8 + 4]) = o1;
        }
    }
}

// ---------------- launch ----------------

extern "C" void kernel_launch(void* const* d_in, const int* in_sizes, int n_in,
                              void* d_out, int out_size, void* d_ws, size_t ws_size,
                              hipStream_t stream) {
    const float* x   = (const float*)d_in[0];
    const int*   ei  = (const int*)d_in[1];
    const float* w1l = (const float*)d_in[2];
    const float* b1l = (const float*)d_in[3];
    const float* w1r = (const float*)d_in[4];
    const float* w2l = (const float*)d_in[5];
    const float* b2l = (const float*)d_in[6];
    const float* w2r = (const float*)d_in[7];
    float* out = (float*)d_out;

    const int n = in_sizes[0] / D;   // 100000
    const int e = in_sizes[1] / 2;   // 1600000
    const int* rowi = ei;            // sources
    const int* coli = ei + e;        // targets

    const int nbkt = (n + 255) >> 8;          // 391 (<=512)
    const int n2 = nbkt * NWG;                // 100096 (multiple of 256)
    const int cpw = (e + NWG - 1) / NWG;      // 6250
    const int nb2 = n2 / 256;                 // 391 (<=512)
    const int PN = ((n + 1 + 63) / 64) * 64;

    int* row_ptr  = (int*)d_ws;               // PN
    int* hist_t   = row_ptr + PN;             // n2
    int* scanned  = hist_t + n2;              // n2
    int* bsum     = scanned + n2;             // 512
    int* srcs     = bsum + 512;               // e
    float* mean   = (float*)(srcs + e);       // n*D floats
    unsigned int* ebuf = (unsigned int*)mean; // e (aliased with mean; dead before agg)

    // CSR build: bucket histogram -> scan -> bucket scatter -> per-bucket CSR
    hist_bucket<<<NWG, 256, 0, stream>>>(coli, hist_t, e, nbkt, cpw);
    scan1<<<nb2, 256, 0, stream>>>(hist_t, scanned, bsum, n2);
    scan2<<<1, 512, 0, stream>>>(bsum, nb2);
    scan3b<<<nb2, 256, 0, stream>>>(scanned, bsum, n2);
    scatter_bucket<<<NWG, 256, 0, stream>>>(rowi, coli, scanned, ebuf, e, nbkt, cpw);
    csr_bucket<<<nbkt, 256, 0, stream>>>(scanned, ebuf, row_ptr, srcs, e, n, nbkt);
    set_end<<<1, 1, 0, stream>>>(row_ptr, n, e);

    const int mm_grid = (n + BM - 1) / BM;

    // layer 1: h = relu(mean(x)@w1l + b1l + x@w1r), h in d_out
    aggregate_mean<<<(n + 3) / 4, 256, 0, stream>>>(x, mean, row_ptr, srcs, n);
    sage_mm<<<mm_grid, 256, 0, stream>>>(mean, x, w1l, b1l, w1r, out, n);

    // layer 2: out = relu(mean(h)@w2l + b2l + h@w2r), in place over h
    aggregate_mean<<<(n + 3) / 4, 256, 0, stream>>>(out, mean, row_ptr, srcs, n);
    sage_mm<<<mm_grid, 256, 0, stream>>>(mean, out, w2l, b2l, w2r, out, n);
}

// Round 5
// 573.297 us; speedup vs baseline: 1.5823x; 1.0178x over previous
//
#include <hip/hip_runtime.h>

#define D 128
#define BM 128
#define KC 32
#define NWG 256  // workgroups in hist/scatter phases

// ---------------- generic scan (256/block) ----------------

__global__ void scan1(const int* __restrict__ in, int* __restrict__ out,
                      int* __restrict__ bsum, int n) {
    __shared__ int s[256];
    int t = threadIdx.x;
    int i = blockIdx.x * 256 + t;
    int v = (i < n) ? in[i] : 0;
    s[t] = v;
    __syncthreads();
    #pragma unroll
    for (int off = 1; off < 256; off <<= 1) {
        int add = (t >= off) ? s[t - off] : 0;
        __syncthreads();
        s[t] += add;
        __syncthreads();
    }
    if (i < n) out[i] = s[t] - v;          // exclusive within block
    if (t == 255) bsum[blockIdx.x] = s[255];
}

__global__ void scan2(int* __restrict__ bsum, int nb) {
    __shared__ int s[512];
    int t = threadIdx.x;
    int v = (t < nb) ? bsum[t] : 0;
    s[t] = v;
    __syncthreads();
    #pragma unroll
    for (int off = 1; off < 512; off <<= 1) {
        int add = (t >= off) ? s[t - off] : 0;
        __syncthreads();
        s[t] += add;
        __syncthreads();
    }
    if (t < nb) bsum[t] = s[t] - v;        // exclusive
}

__global__ void scan3b(int* __restrict__ out, const int* __restrict__ bsum, int n) {
    int i = blockIdx.x * blockDim.x + threadIdx.x;
    if (i < n) out[i] += bsum[i >> 8];
}

__global__ void set_end(int* __restrict__ row_ptr, int n, int e) {
    row_ptr[n] = e;
}

// ---------------- phase A: bucket histogram + scatter ----------------

__global__ __launch_bounds__(256) void hist_bucket(const int* __restrict__ coli,
                                                   int* __restrict__ hist_t,
                                                   int e, int nbkt, int cpw) {
    __shared__ int hist[512];
    int w = blockIdx.x, tid = threadIdx.x;
    for (int b = tid; b < nbkt; b += 256) hist[b] = 0;
    __syncthreads();
    int i1 = min((w + 1) * cpw, e);
    for (int i = w * cpw + tid; i < i1; i += 256)
        atomicAdd(&hist[coli[i] >> 8], 1);
    __syncthreads();
    for (int b = tid; b < nbkt; b += 256) hist_t[b * NWG + w] = hist[b];
}

__global__ __launch_bounds__(256) void scatter_bucket(const int* __restrict__ rowi,
                                                      const int* __restrict__ coli,
                                                      const int* __restrict__ scanned,
                                                      unsigned int* __restrict__ ebuf,
                                                      int e, int nbkt, int cpw) {
    __shared__ int cur[512];
    int w = blockIdx.x, tid = threadIdx.x;
    for (int b = tid; b < nbkt; b += 256) cur[b] = scanned[b * NWG + w];
    __syncthreads();
    int i1 = min((w + 1) * cpw, e);
    for (int i = w * cpw + tid; i < i1; i += 256) {
        int c = coli[i];
        int b = c >> 8;
        int p = atomicAdd(&cur[b], 1);
        ebuf[p] = ((unsigned int)rowi[i] << 8) | (unsigned int)(c & 255);
    }
}

// ---------------- phase B: per-bucket local CSR ----------------
__global__ __launch_bounds__(256) void csr_bucket(const int* __restrict__ scanned,
                                                  const unsigned int* __restrict__ ebuf,
                                                  int* __restrict__ row_ptr,
                                                  int* __restrict__ srcs,
                                                  int e, int n, int nbkt) {
    __shared__ int cnt[256], s[256], cur[256];
    int b = blockIdx.x, tid = threadIdx.x;
    int S = scanned[b * NWG];
    int Send = (b == nbkt - 1) ? e : scanned[(b + 1) * NWG];
    cnt[tid] = 0;
    __syncthreads();
    for (int i = S + tid; i < Send; i += 256)
        atomicAdd(&cnt[ebuf[i] & 255], 1);
    __syncthreads();
    int v = cnt[tid];
    s[tid] = v;
    __syncthreads();
    #pragma unroll
    for (int off = 1; off < 256; off <<= 1) {
        int add = (tid >= off) ? s[tid - off] : 0;
        __syncthreads();
        s[tid] += add;
        __syncthreads();
    }
    int offx = s[tid] - v;
    int node = b * 256 + tid;
    if (node < n) row_ptr[node] = S + offx;
    cur[tid] = offx;
    __syncthreads();
    for (int i = S + tid; i < Send; i += 256) {
        unsigned int pe = ebuf[i];
        int lc = (int)(pe & 255u);
        int p = S + atomicAdd(&cur[lc], 1);
        srcs[p] = (int)(pe >> 8);
    }
}

// ---------------- mean aggregation (unchanged) ----------------
__global__ __launch_bounds__(256) void aggregate_mean(
    const float* __restrict__ x, float* __restrict__ mean,
    const int* __restrict__ row_ptr, const int* __restrict__ srcs, int n) {
    int node = blockIdx.x * 4 + (threadIdx.x >> 6);
    if (node >= n) return;
    int lane = threadIdx.x & 63;
    int half = lane >> 5;
    int l32 = lane & 31;
    int beg = row_ptr[node];
    int end = row_ptr[node + 1];

    float4 a0 = make_float4(0.f, 0.f, 0.f, 0.f);
    float4 a1 = make_float4(0.f, 0.f, 0.f, 0.f);
    float4 a2 = make_float4(0.f, 0.f, 0.f, 0.f);
    float4 a3 = make_float4(0.f, 0.f, 0.f, 0.f);
    int j = beg;
    for (; j + 8 <= end; j += 8) {
        int s0 = srcs[j + half];
        int s1 = srcs[j + 2 + half];
        int s2 = srcs[j + 4 + half];
        int s3 = srcs[j + 6 + half];
        float4 v0 = *reinterpret_cast<const float4*>(x + (size_t)s0 * D + l32 * 4);
        float4 v1 = *reinterpret_cast<const float4*>(x + (size_t)s1 * D + l32 * 4);
        float4 v2 = *reinterpret_cast<const float4*>(x + (size_t)s2 * D + l32 * 4);
        float4 v3 = *reinterpret_cast<const float4*>(x + (size_t)s3 * D + l32 * 4);
        a0.x += v0.x; a0.y += v0.y; a0.z += v0.z; a0.w += v0.w;
        a1.x += v1.x; a1.y += v1.y; a1.z += v1.z; a1.w += v1.w;
        a2.x += v2.x; a2.y += v2.y; a2.z += v2.z; a2.w += v2.w;
        a3.x += v3.x; a3.y += v3.y; a3.z += v3.z; a3.w += v3.w;
    }
    if (j + 4 <= end) {
        int s0 = srcs[j + half];
        int s1 = srcs[j + 2 + half];
        float4 v0 = *reinterpret_cast<const float4*>(x + (size_t)s0 * D + l32 * 4);
        float4 v1 = *reinterpret_cast<const float4*>(x + (size_t)s1 * D + l32 * 4);
        a0.x += v0.x; a0.y += v0.y; a0.z += v0.z; a0.w += v0.w;
        a1.x += v1.x; a1.y += v1.y; a1.z += v1.z; a1.w += v1.w;
        j += 4;
    }
    if (j + 2 <= end) {
        int s0 = srcs[j + half];
        float4 v0 = *reinterpret_cast<const float4*>(x + (size_t)s0 * D + l32 * 4);
        a0.x += v0.x; a0.y += v0.y; a0.z += v0.z; a0.w += v0.w;
        j += 2;
    }
    if (j < end && half == 0) {
        int s0 = srcs[j];
        float4 v0 = *reinterpret_cast<const float4*>(x + (size_t)s0 * D + l32 * 4);
        a0.x += v0.x; a0.y += v0.y; a0.z += v0.z; a0.w += v0.w;
    }
    a0.x += a1.x + a2.x + a3.x;
    a0.y += a1.y + a2.y + a3.y;
    a0.z += a1.z + a2.z + a3.z;
    a0.w += a1.w + a2.w + a3.w;
    a0.x += __shfl_xor(a0.x, 32, 64);
    a0.y += __shfl_xor(a0.y, 32, 64);
    a0.z += __shfl_xor(a0.z, 32, 64);
    a0.w += __shfl_xor(a0.w, 32, 64);

    if (half == 0) {
        float inv = 1.0f / fmaxf((float)(end - beg), 1.0f);
        float4 o;
        o.x = a0.x * inv; o.y = a0.y * inv; o.z = a0.z * inv; o.w = a0.w * inv;
        *reinterpret_cast<float4*>(mean + (size_t)node * D + l32 * 4) = o;
    }
}

// ---------------- fused dual-GEMM + bias + relu, v2 ----------------
// 128 threads/block, BM=128, per-thread 8 rows x 16 cols.
// A staged k-major [32][132] (2-way reads, free); B reads col-split
// (tc*4 + 32q) -> all 8 bank-quads covered, conflict-free.
// A chunk c+1 prefetched into regs during compute of chunk c.
__device__ inline void fma4(float4& d, float a, const float4& b) {
    d.x += a * b.x; d.y += a * b.y; d.z += a * b.z; d.w += a * b.w;
}

__global__ __launch_bounds__(128, 2) void sage_mm(
    const float* __restrict__ mean, const float* __restrict__ xin,
    const float* __restrict__ wl, const float* __restrict__ bias,
    const float* __restrict__ wr, float* __restrict__ out, int n) {
    __shared__ float smA[KC * 132];   // [k][row], 16.9 KB
    __shared__ float smB[KC * 132];   // [k][col], 16.9 KB
    const int tid = threadIdx.x;
    const int row0 = blockIdx.x * BM;
    const int tc = tid & 7;           // col group: cols tc*4 + {0,32,64,96}
    const int tr = tid >> 3;          // row group: rows tr*8 .. tr*8+7

    float4 acc[8][4];
    #pragma unroll
    for (int q = 0; q < 4; ++q) {
        float4 b = *reinterpret_cast<const float4*>(&bias[q * 32 + tc * 4]);
        #pragma unroll
        for (int r = 0; r < 8; ++r) acc[r][q] = b;
    }

    float4 pa[8];
    // prologue: prefetch A chunk 0 (mean, k0=0)
    #pragma unroll
    for (int i = 0; i < 8; ++i) {
        int f = tid + i * 128;
        int row = f >> 3, kq = f & 7;
        int gr = row0 + row;
        pa[i] = (gr < n) ? *reinterpret_cast<const float4*>(&mean[(size_t)gr * D + kq * 4])
                         : make_float4(0.f, 0.f, 0.f, 0.f);
    }

    for (int c = 0; c < 8; ++c) {
        const float* __restrict__ bsrc = (c < 4) ? wl : wr;
        const int k0 = (c & 3) * KC;
        // write prefetched A chunk to LDS, transposed to [k][row]
        #pragma unroll
        for (int i = 0; i < 8; ++i) {
            int f = tid + i * 128;
            int row = f >> 3, kq = f & 7;
            smA[(kq * 4 + 0) * 132 + row] = pa[i].x;
            smA[(kq * 4 + 1) * 132 + row] = pa[i].y;
            smA[(kq * 4 + 2) * 132 + row] = pa[i].z;
            smA[(kq * 4 + 3) * 132 + row] = pa[i].w;
        }
        // stage B chunk [32 k][128 c] (weights, L2-hot)
        #pragma unroll
        for (int i = 0; i < 8; ++i) {
            int f = tid + i * 128;
            int bk = f >> 5, c4 = f & 31;
            *reinterpret_cast<float4*>(&smB[bk * 132 + c4 * 4]) =
                *reinterpret_cast<const float4*>(&bsrc[(size_t)(k0 + bk) * D + c4 * 4]);
        }
        __syncthreads();
        // prefetch next A chunk into regs (latency hides under k-loop)
        if (c < 7) {
            const float* __restrict__ anext = (c + 1 < 4) ? mean : xin;
            const int k1 = ((c + 1) & 3) * KC;
            #pragma unroll
            for (int i = 0; i < 8; ++i) {
                int f = tid + i * 128;
                int row = f >> 3, kq = f & 7;
                int gr = row0 + row;
                pa[i] = (gr < n) ? *reinterpret_cast<const float4*>(&anext[(size_t)gr * D + k1 + kq * 4])
                                 : make_float4(0.f, 0.f, 0.f, 0.f);
            }
        }
        // compute: 32 k-steps, 128 FMA each
        #pragma unroll 8
        for (int k = 0; k < KC; ++k) {
            float4 a0 = *reinterpret_cast<const float4*>(&smA[k * 132 + tr * 8]);
            float4 a1 = *reinterpret_cast<const float4*>(&smA[k * 132 + tr * 8 + 4]);
            float4 bq[4];
            #pragma unroll
            for (int q = 0; q < 4; ++q)
                bq[q] = *reinterpret_cast<const float4*>(&smB[k * 132 + q * 32 + tc * 4]);
            #pragma unroll
            for (int q = 0; q < 4; ++q) {
                fma4(acc[0][q], a0.x, bq[q]);
                fma4(acc[1][q], a0.y, bq[q]);
                fma4(acc[2][q], a0.z, bq[q]);
                fma4(acc[3][q], a0.w, bq[q]);
                fma4(acc[4][q], a1.x, bq[q]);
                fma4(acc[5][q], a1.y, bq[q]);
                fma4(acc[6][q], a1.z, bq[q]);
                fma4(acc[7][q], a1.w, bq[q]);
            }
        }
        __syncthreads();
    }

    #pragma unroll
    for (int r = 0; r < 8; ++r) {
        int gr = row0 + tr * 8 + r;
        if (gr < n) {
            #pragma unroll
            for (int q = 0; q < 4; ++q) {
                float4 o = acc[r][q];
                o.x = fmaxf(o.x, 0.f); o.y = fmaxf(o.y, 0.f);
                o.z = fmaxf(o.z, 0.f); o.w = fmaxf(o.w, 0.f);
                *reinterpret_cast<float4*>(&out[(size_t)gr * D + q * 32 + tc * 4]) = o;
            }
        }
    }
}

// ---------------- launch ----------------

extern "C" void kernel_launch(void* const* d_in, const int* in_sizes, int n_in,
                              void* d_out, int out_size, void* d_ws, size_t ws_size,
                              hipStream_t stream) {
    const float* x   = (const float*)d_in[0];
    const int*   ei  = (const int*)d_in[1];
    const float* w1l = (const float*)d_in[2];
    const float* b1l = (const float*)d_in[3];
    const float* w1r = (const float*)d_in[4];
    const float* w2l = (const float*)d_in[5];
    const float* b2l = (const float*)d_in[6];
    const float* w2r = (const float*)d_in[7];
    float* out = (float*)d_out;

    const int n = in_sizes[0] / D;   // 100000
    const int e = in_sizes[1] / 2;   // 1600000
    const int* rowi = ei;            // sources
    const int* coli = ei + e;        // targets

    const int nbkt = (n + 255) >> 8;          // 391 (<=512)
    const int n2 = nbkt * NWG;                // 100096
    const int cpw = (e + NWG - 1) / NWG;      // 6250
    const int nb2 = n2 / 256;                 // 391 (<=512)
    const int PN = ((n + 1 + 63) / 64) * 64;

    int* row_ptr  = (int*)d_ws;               // PN
    int* hist_t   = row_ptr + PN;             // n2
    int* scanned  = hist_t + n2;              // n2
    int* bsum     = scanned + n2;             // 512
    int* srcs     = bsum + 512;               // e
    float* mean   = (float*)(srcs + e);       // n*D floats
    unsigned int* ebuf = (unsigned int*)mean; // e (aliased; dead before agg)

    hist_bucket<<<NWG, 256, 0, stream>>>(coli, hist_t, e, nbkt, cpw);
    scan1<<<nb2, 256, 0, stream>>>(hist_t, scanned, bsum, n2);
    scan2<<<1, 512, 0, stream>>>(bsum, nb2);
    scan3b<<<nb2, 256, 0, stream>>>(scanned, bsum, n2);
    scatter_bucket<<<NWG, 256, 0, stream>>>(rowi, coli, scanned, ebuf, e, nbkt, cpw);
    csr_bucket<<<nbkt, 256, 0, stream>>>(scanned, ebuf, row_ptr, srcs, e, n, nbkt);
    set_end<<<1, 1, 0, stream>>>(row_ptr, n, e);

    const int mm_grid = (n + BM - 1) / BM;

    // layer 1: h = relu(mean(x)@w1l + b1l + x@w1r), h in d_out
    aggregate_mean<<<(n + 3) / 4, 256, 0, stream>>>(x, mean, row_ptr, srcs, n);
    sage_mm<<<mm_grid, 128, 0, stream>>>(mean, x, w1l, b1l, w1r, out, n);

    // layer 2: out = relu(mean(h)@w2l + b2l + h@w2r), in place over h
    aggregate_mean<<<(n + 3) / 4, 256, 0, stream>>>(out, mean, row_ptr, srcs, n);
    sage_mm<<<mm_grid, 128, 0, stream>>>(mean, out, w2l, b2l, w2r, out, n);
}

// Round 6
// 510.476 us; speedup vs baseline: 1.7770x; 1.1231x over previous
//
#include <hip/hip_runtime.h>

#define D 128
#define BM 128
#define NWG 256  // workgroups in hist/scatter phases

typedef short short8 __attribute__((ext_vector_type(8)));
typedef float f32x4 __attribute__((ext_vector_type(4)));

__device__ inline unsigned short f2bf_rne(float x) {
    unsigned int b = __float_as_uint(x);
    unsigned int r = (b + 0x7FFFu + ((b >> 16) & 1u)) >> 16;
    return (unsigned short)r;
}
__device__ inline float bf2f(unsigned short h) {
    return __uint_as_float(((unsigned int)h) << 16);
}

// ---------------- generic scan (256/block) ----------------

__global__ void scan1(const int* __restrict__ in, int* __restrict__ out,
                      int* __restrict__ bsum, int n) {
    __shared__ int s[256];
    int t = threadIdx.x;
    int i = blockIdx.x * 256 + t;
    int v = (i < n) ? in[i] : 0;
    s[t] = v;
    __syncthreads();
    #pragma unroll
    for (int off = 1; off < 256; off <<= 1) {
        int add = (t >= off) ? s[t - off] : 0;
        __syncthreads();
        s[t] += add;
        __syncthreads();
    }
    if (i < n) out[i] = s[t] - v;
    if (t == 255) bsum[blockIdx.x] = s[255];
}

__global__ void scan2(int* __restrict__ bsum, int nb) {
    __shared__ int s[512];
    int t = threadIdx.x;
    int v = (t < nb) ? bsum[t] : 0;
    s[t] = v;
    __syncthreads();
    #pragma unroll
    for (int off = 1; off < 512; off <<= 1) {
        int add = (t >= off) ? s[t - off] : 0;
        __syncthreads();
        s[t] += add;
        __syncthreads();
    }
    if (t < nb) bsum[t] = s[t] - v;
}

__global__ void scan3b(int* __restrict__ out, const int* __restrict__ bsum, int n) {
    int i = blockIdx.x * blockDim.x + threadIdx.x;
    if (i < n) out[i] += bsum[i >> 8];
}

__global__ void set_end(int* __restrict__ row_ptr, int n, int e) {
    row_ptr[n] = e;
}

// ---------------- phase A: bucket histogram + scatter ----------------

__global__ __launch_bounds__(256) void hist_bucket(const int* __restrict__ coli,
                                                   int* __restrict__ hist_t,
                                                   int e, int nbkt, int cpw) {
    __shared__ int hist[512];
    int w = blockIdx.x, tid = threadIdx.x;
    for (int b = tid; b < nbkt; b += 256) hist[b] = 0;
    __syncthreads();
    int i1 = min((w + 1) * cpw, e);
    for (int i = w * cpw + tid; i < i1; i += 256)
        atomicAdd(&hist[coli[i] >> 8], 1);
    __syncthreads();
    for (int b = tid; b < nbkt; b += 256) hist_t[b * NWG + w] = hist[b];
}

__global__ __launch_bounds__(256) void scatter_bucket(const int* __restrict__ rowi,
                                                      const int* __restrict__ coli,
                                                      const int* __restrict__ scanned,
                                                      unsigned int* __restrict__ ebuf,
                                                      int e, int nbkt, int cpw) {
    __shared__ int cur[512];
    int w = blockIdx.x, tid = threadIdx.x;
    for (int b = tid; b < nbkt; b += 256) cur[b] = scanned[b * NWG + w];
    __syncthreads();
    int i1 = min((w + 1) * cpw, e);
    for (int i = w * cpw + tid; i < i1; i += 256) {
        int c = coli[i];
        int b = c >> 8;
        int p = atomicAdd(&cur[b], 1);
        ebuf[p] = ((unsigned int)rowi[i] << 8) | (unsigned int)(c & 255);
    }
}

// ---------------- phase B: per-bucket local CSR ----------------
__global__ __launch_bounds__(256) void csr_bucket(const int* __restrict__ scanned,
                                                  const unsigned int* __restrict__ ebuf,
                                                  int* __restrict__ row_ptr,
                                                  int* __restrict__ srcs,
                                                  int e, int n, int nbkt) {
    __shared__ int cnt[256], s[256], cur[256];
    int b = blockIdx.x, tid = threadIdx.x;
    int S = scanned[b * NWG];
    int Send = (b == nbkt - 1) ? e : scanned[(b + 1) * NWG];
    cnt[tid] = 0;
    __syncthreads();
    for (int i = S + tid; i < Send; i += 256)
        atomicAdd(&cnt[ebuf[i] & 255], 1);
    __syncthreads();
    int v = cnt[tid];
    s[tid] = v;
    __syncthreads();
    #pragma unroll
    for (int off = 1; off < 256; off <<= 1) {
        int add = (tid >= off) ? s[tid - off] : 0;
        __syncthreads();
        s[tid] += add;
        __syncthreads();
    }
    int offx = s[tid] - v;
    int node = b * 256 + tid;
    if (node < n) row_ptr[node] = S + offx;
    cur[tid] = offx;
    __syncthreads();
    for (int i = S + tid; i < Send; i += 256) {
        unsigned int pe = ebuf[i];
        int lc = (int)(pe & 255u);
        int p = S + atomicAdd(&cur[lc], 1);
        srcs[p] = (int)(pe >> 8);
    }
}

// ---------------- mean aggregation (unchanged) ----------------
__global__ __launch_bounds__(256) void aggregate_mean(
    const float* __restrict__ x, float* __restrict__ mean,
    const int* __restrict__ row_ptr, const int* __restrict__ srcs, int n) {
    int node = blockIdx.x * 4 + (threadIdx.x >> 6);
    if (node >= n) return;
    int lane = threadIdx.x & 63;
    int half = lane >> 5;
    int l32 = lane & 31;
    int beg = row_ptr[node];
    int end = row_ptr[node + 1];

    float4 a0 = make_float4(0.f, 0.f, 0.f, 0.f);
    float4 a1 = make_float4(0.f, 0.f, 0.f, 0.f);
    float4 a2 = make_float4(0.f, 0.f, 0.f, 0.f);
    float4 a3 = make_float4(0.f, 0.f, 0.f, 0.f);
    int j = beg;
    for (; j + 8 <= end; j += 8) {
        int s0 = srcs[j + half];
        int s1 = srcs[j + 2 + half];
        int s2 = srcs[j + 4 + half];
        int s3 = srcs[j + 6 + half];
        float4 v0 = *reinterpret_cast<const float4*>(x + (size_t)s0 * D + l32 * 4);
        float4 v1 = *reinterpret_cast<const float4*>(x + (size_t)s1 * D + l32 * 4);
        float4 v2 = *reinterpret_cast<const float4*>(x + (size_t)s2 * D + l32 * 4);
        float4 v3 = *reinterpret_cast<const float4*>(x + (size_t)s3 * D + l32 * 4);
        a0.x += v0.x; a0.y += v0.y; a0.z += v0.z; a0.w += v0.w;
        a1.x += v1.x; a1.y += v1.y; a1.z += v1.z; a1.w += v1.w;
        a2.x += v2.x; a2.y += v2.y; a2.z += v2.z; a2.w += v2.w;
        a3.x += v3.x; a3.y += v3.y; a3.z += v3.z; a3.w += v3.w;
    }
    if (j + 4 <= end) {
        int s0 = srcs[j + half];
        int s1 = srcs[j + 2 + half];
        float4 v0 = *reinterpret_cast<const float4*>(x + (size_t)s0 * D + l32 * 4);
        float4 v1 = *reinterpret_cast<const float4*>(x + (size_t)s1 * D + l32 * 4);
        a0.x += v0.x; a0.y += v0.y; a0.z += v0.z; a0.w += v0.w;
        a1.x += v1.x; a1.y += v1.y; a1.z += v1.z; a1.w += v1.w;
        j += 4;
    }
    if (j + 2 <= end) {
        int s0 = srcs[j + half];
        float4 v0 = *reinterpret_cast<const float4*>(x + (size_t)s0 * D + l32 * 4);
        a0.x += v0.x; a0.y += v0.y; a0.z += v0.z; a0.w += v0.w;
        j += 2;
    }
    if (j < end && half == 0) {
        int s0 = srcs[j];
        float4 v0 = *reinterpret_cast<const float4*>(x + (size_t)s0 * D + l32 * 4);
        a0.x += v0.x; a0.y += v0.y; a0.z += v0.z; a0.w += v0.w;
    }
    a0.x += a1.x + a2.x + a3.x;
    a0.y += a1.y + a2.y + a3.y;
    a0.z += a1.z + a2.z + a3.z;
    a0.w += a1.w + a2.w + a3.w;
    a0.x += __shfl_xor(a0.x, 32, 64);
    a0.y += __shfl_xor(a0.y, 32, 64);
    a0.z += __shfl_xor(a0.z, 32, 64);
    a0.w += __shfl_xor(a0.w, 32, 64);

    if (half == 0) {
        float inv = 1.0f / fmaxf((float)(end - beg), 1.0f);
        float4 o;
        o.x = a0.x * inv; o.y = a0.y * inv; o.z = a0.z * inv; o.w = a0.w * inv;
        *reinterpret_cast<float4*>(mean + (size_t)node * D + l32 * 4) = o;
    }
}

// ---------------- weight prep: split + transpose ----------------
// Wt[layer][hi/lo][n=128][k=256] bf16, k 0..127 <- wl[k][n], 128..255 <- wr[k-128][n]
__global__ __launch_bounds__(256) void split_w(const float* __restrict__ w1l,
                                               const float* __restrict__ w1r,
                                               const float* __restrict__ w2l,
                                               const float* __restrict__ w2r,
                                               short* __restrict__ wt) {
    int b = blockIdx.x;           // 0..255 = layer*128 + n
    int layer = b >> 7;
    int nn = b & 127;
    int k = threadIdx.x;          // 0..255
    const float* wl = layer ? w2l : w1l;
    const float* wr = layer ? w2r : w1r;
    float v = (k < 128) ? wl[k * D + nn] : wr[(k - 128) * D + nn];
    unsigned short h = f2bf_rne(v);
    float lo = v - bf2f(h);
    unsigned short l = f2bf_rne(lo);
    short* base = wt + layer * 65536;
    base[nn * 256 + k] = (short)h;
    base[32768 + nn * 256 + k] = (short)l;
}

// ---------------- MFMA dual-GEMM + bias + relu ----------------
// C[n][128] = [mean|xin]@[wl;wr] via 3-term bf16x2 split:
//   A@B ~= Ah@Bh + Al@Bh + Ah@Bl      (error ~2^-17, fp32 accum)
// BM=128, 256 thr = 4 waves; wave w owns rows w*32..w*32+31 (2x8 frags 16x16).
// LDS rows padded to 40 bf16 (80B, 16B-aligned, ~2-way banks).
__global__ __launch_bounds__(256, 2) void sage_mm_mfma(
    const float* __restrict__ mean, const float* __restrict__ xin,
    const short* __restrict__ wth, const short* __restrict__ wtl,
    const float* __restrict__ bias, float* __restrict__ out, int n) {
    __shared__ short sAh[128 * 40];
    __shared__ short sAl[128 * 40];
    __shared__ short sBh[128 * 40];
    __shared__ short sBl[128 * 40];
    const int tid = threadIdx.x;
    const int wave = tid >> 6;
    const int lane = tid & 63;
    const int l15 = lane & 15;
    const int kg = lane >> 4;
    const int row0 = blockIdx.x * BM;

    f32x4 acc[2][8];
    #pragma unroll
    for (int fr = 0; fr < 2; ++fr)
        #pragma unroll
        for (int fc = 0; fc < 8; ++fc)
            acc[fr][fc] = (f32x4){0.f, 0.f, 0.f, 0.f};

    float4 pa[4];
    int4 pbh[2], pbl[2];

    // prologue: prefetch chunk 0 (A from mean, B at k0=0)
    #pragma unroll
    for (int i = 0; i < 4; ++i) {
        int f = tid + i * 256;
        int row = f >> 3, k4 = f & 7;
        int gr = row0 + row;
        pa[i] = (gr < n) ? *reinterpret_cast<const float4*>(&mean[(size_t)gr * D + k4 * 4])
                         : make_float4(0.f, 0.f, 0.f, 0.f);
    }
    #pragma unroll
    for (int i = 0; i < 2; ++i) {
        int f = tid + i * 256;
        int n_ = f >> 2, kq = f & 3;
        pbh[i] = *reinterpret_cast<const int4*>(&wth[n_ * 256 + kq * 8]);
        pbl[i] = *reinterpret_cast<const int4*>(&wtl[n_ * 256 + kq * 8]);
    }

    for (int c = 0; c < 8; ++c) {
        // write prefetched A (convert fp32 -> hi/lo bf16) and B to LDS
        #pragma unroll
        for (int i = 0; i < 4; ++i) {
            int f = tid + i * 256;
            int row = f >> 3, k4 = f & 7;
            const float* pv = &pa[i].x;
            unsigned short h[4], l[4];
            #pragma unroll
            for (int j = 0; j < 4; ++j) {
                float v = pv[j];
                h[j] = f2bf_rne(v);
                l[j] = f2bf_rne(v - bf2f(h[j]));
            }
            short* dsth = &sAh[row * 40 + k4 * 4];
            short* dstl = &sAl[row * 40 + k4 * 4];
            #pragma unroll
            for (int j = 0; j < 4; ++j) { dsth[j] = (short)h[j]; dstl[j] = (short)l[j]; }
        }
        #pragma unroll
        for (int i = 0; i < 2; ++i) {
            int f = tid + i * 256;
            int n_ = f >> 2, kq = f & 3;
            *reinterpret_cast<int4*>(&sBh[n_ * 40 + kq * 8]) = pbh[i];
            *reinterpret_cast<int4*>(&sBl[n_ * 40 + kq * 8]) = pbl[i];
        }
        __syncthreads();

        // prefetch next chunk into regs (hides under MFMAs)
        if (c < 7) {
            const float* __restrict__ anext = (c + 1 < 4) ? mean : xin;
            const int ka = ((c + 1) & 3) * 32;
            const int kb = (c + 1) * 32;
            #pragma unroll
            for (int i = 0; i < 4; ++i) {
                int f = tid + i * 256;
                int row = f >> 3, k4 = f & 7;
                int gr = row0 + row;
                pa[i] = (gr < n) ? *reinterpret_cast<const float4*>(&anext[(size_t)gr * D + ka + k4 * 4])
                                 : make_float4(0.f, 0.f, 0.f, 0.f);
            }
            #pragma unroll
            for (int i = 0; i < 2; ++i) {
                int f = tid + i * 256;
                int n_ = f >> 2, kq = f & 3;
                pbh[i] = *reinterpret_cast<const int4*>(&wth[n_ * 256 + kb + kq * 8]);
                pbl[i] = *reinterpret_cast<const int4*>(&wtl[n_ * 256 + kb + kq * 8]);
            }
        }

        // compute: 2 row-frags x 8 col-frags x 3 terms = 48 MFMA
        short8 ah[2], al[2];
        #pragma unroll
        for (int fr = 0; fr < 2; ++fr) {
            int r = wave * 32 + fr * 16 + l15;
            ah[fr] = *reinterpret_cast<const short8*>(&sAh[r * 40 + kg * 8]);
            al[fr] = *reinterpret_cast<const short8*>(&sAl[r * 40 + kg * 8]);
        }
        #pragma unroll
        for (int fc = 0; fc < 8; ++fc) {
            int cc = fc * 16 + l15;
            short8 bh = *reinterpret_cast<const short8*>(&sBh[cc * 40 + kg * 8]);
            short8 bl = *reinterpret_cast<const short8*>(&sBl[cc * 40 + kg * 8]);
            #pragma unroll
            for (int fr = 0; fr < 2; ++fr) {
                acc[fr][fc] = __builtin_amdgcn_mfma_f32_16x16x32_bf16(ah[fr], bh, acc[fr][fc], 0, 0, 0);
                acc[fr][fc] = __builtin_amdgcn_mfma_f32_16x16x32_bf16(al[fr], bh, acc[fr][fc], 0, 0, 0);
                acc[fr][fc] = __builtin_amdgcn_mfma_f32_16x16x32_bf16(ah[fr], bl, acc[fr][fc], 0, 0, 0);
            }
        }
        __syncthreads();
    }

    // epilogue: bias + relu + store
    float bz[8];
    #pragma unroll
    for (int fc = 0; fc < 8; ++fc) bz[fc] = bias[fc * 16 + l15];
    #pragma unroll
    for (int fr = 0; fr < 2; ++fr) {
        #pragma unroll
        for (int j = 0; j < 4; ++j) {
            int gr = row0 + wave * 32 + fr * 16 + kg * 4 + j;
            if (gr < n) {
                #pragma unroll
                for (int fc = 0; fc < 8; ++fc)
                    out[(size_t)gr * D + fc * 16 + l15] = fmaxf(acc[fr][fc][j] + bz[fc], 0.f);
            }
        }
    }
}

// ---------------- launch ----------------

extern "C" void kernel_launch(void* const* d_in, const int* in_sizes, int n_in,
                              void* d_out, int out_size, void* d_ws, size_t ws_size,
                              hipStream_t stream) {
    const float* x   = (const float*)d_in[0];
    const int*   ei  = (const int*)d_in[1];
    const float* w1l = (const float*)d_in[2];
    const float* b1l = (const float*)d_in[3];
    const float* w1r = (const float*)d_in[4];
    const float* w2l = (const float*)d_in[5];
    const float* b2l = (const float*)d_in[6];
    const float* w2r = (const float*)d_in[7];
    float* out = (float*)d_out;

    const int n = in_sizes[0] / D;   // 100000
    const int e = in_sizes[1] / 2;   // 1600000
    const int* rowi = ei;            // sources
    const int* coli = ei + e;        // targets

    const int nbkt = (n + 255) >> 8;          // 391 (<=512)
    const int n2 = nbkt * NWG;                // 100096
    const int cpw = (e + NWG - 1) / NWG;      // 6250
    const int nb2 = n2 / 256;                 // 391
    const int PN = ((n + 1 + 63) / 64) * 64;

    int* row_ptr  = (int*)d_ws;               // PN
    int* hist_t   = row_ptr + PN;             // n2
    int* scanned  = hist_t + n2;              // n2
    int* bsum     = scanned + n2;             // 512
    int* srcs     = bsum + 512;               // e
    short* wt     = (short*)(srcs + e);       // 4 * 32768 shorts (256KB)
    float* mean   = (float*)(wt + 4 * 32768); // n*D floats
    unsigned int* ebuf = (unsigned int*)mean; // e (aliased; dead before agg)

    // weight split/transpose (independent of CSR)
    split_w<<<256, 256, 0, stream>>>(w1l, w1r, w2l, w2r, wt);

    // CSR build
    hist_bucket<<<NWG, 256, 0, stream>>>(coli, hist_t, e, nbkt, cpw);
    scan1<<<nb2, 256, 0, stream>>>(hist_t, scanned, bsum, n2);
    scan2<<<1, 512, 0, stream>>>(bsum, nb2);
    scan3b<<<nb2, 256, 0, stream>>>(scanned, bsum, n2);
    scatter_bucket<<<NWG, 256, 0, stream>>>(rowi, coli, scanned, ebuf, e, nbkt, cpw);
    csr_bucket<<<nbkt, 256, 0, stream>>>(scanned, ebuf, row_ptr, srcs, e, n, nbkt);
    set_end<<<1, 1, 0, stream>>>(row_ptr, n, e);

    const int mm_grid = (n + BM - 1) / BM;

    // layer 1: h = relu(mean(x)@w1l + b1l + x@w1r), h in d_out
    aggregate_mean<<<(n + 3) / 4, 256, 0, stream>>>(x, mean, row_ptr, srcs, n);
    sage_mm_mfma<<<mm_grid, 256, 0, stream>>>(mean, x, wt, wt + 32768, b1l, out, n);

    // layer 2: out = relu(mean(h)@w2l + b2l + h@w2r), in place over h
    aggregate_mean<<<(n + 3) / 4, 256, 0, stream>>>(out, mean, row_ptr, srcs, n);
    sage_mm_mfma<<<mm_grid, 256, 0, stream>>>(mean, out, wt + 65536, wt + 98304, b2l, out, n);
}

// Round 8
// 504.822 us; speedup vs baseline: 1.7969x; 1.0112x over previous
//
#include <hip/hip_runtime.h>

#define D 128
#define BM 128
#define NWG 256  // workgroups in hist/scatter phases

typedef short short8 __attribute__((ext_vector_type(8)));
typedef float f32x4 __attribute__((ext_vector_type(4)));

__device__ inline unsigned short f2bf_rne(float x) {
    unsigned int b = __float_as_uint(x);
    unsigned int r = (b + 0x7FFFu + ((b >> 16) & 1u)) >> 16;
    return (unsigned short)r;
}
__device__ inline float bf2f(unsigned short h) {
    return __uint_as_float(((unsigned int)h) << 16);
}

// ---------------- generic scan (256/block) ----------------

__global__ void scan1(const int* __restrict__ in, int* __restrict__ out,
                      int* __restrict__ bsum, int n) {
    __shared__ int s[256];
    int t = threadIdx.x;
    int i = blockIdx.x * 256 + t;
    int v = (i < n) ? in[i] : 0;
    s[t] = v;
    __syncthreads();
    #pragma unroll
    for (int off = 1; off < 256; off <<= 1) {
        int add = (t >= off) ? s[t - off] : 0;
        __syncthreads();
        s[t] += add;
        __syncthreads();
    }
    if (i < n) out[i] = s[t] - v;
    if (t == 255) bsum[blockIdx.x] = s[255];
}

__global__ void scan2(int* __restrict__ bsum, int nb) {
    __shared__ int s[512];
    int t = threadIdx.x;
    int v = (t < nb) ? bsum[t] : 0;
    s[t] = v;
    __syncthreads();
    #pragma unroll
    for (int off = 1; off < 512; off <<= 1) {
        int add = (t >= off) ? s[t - off] : 0;
        __syncthreads();
        s[t] += add;
        __syncthreads();
    }
    if (t < nb) bsum[t] = s[t] - v;
}

__global__ void scan3b(int* __restrict__ out, const int* __restrict__ bsum, int n) {
    int i = blockIdx.x * blockDim.x + threadIdx.x;
    if (i < n) out[i] += bsum[i >> 8];
}

__global__ void set_end(int* __restrict__ row_ptr, int n, int e) {
    row_ptr[n] = e;
}

// ---------------- phase A: bucket histogram + scatter ----------------

__global__ __launch_bounds__(256) void hist_bucket(const int* __restrict__ coli,
                                                   int* __restrict__ hist_t,
                                                   int e, int nbkt, int cpw) {
    __shared__ int hist[512];
    int w = blockIdx.x, tid = threadIdx.x;
    for (int b = tid; b < nbkt; b += 256) hist[b] = 0;
    __syncthreads();
    int i1 = min((w + 1) * cpw, e);
    for (int i = w * cpw + tid; i < i1; i += 256)
        atomicAdd(&hist[coli[i] >> 8], 1);
    __syncthreads();
    for (int b = tid; b < nbkt; b += 256) hist_t[b * NWG + w] = hist[b];
}

__global__ __launch_bounds__(256) void scatter_bucket(const int* __restrict__ rowi,
                                                      const int* __restrict__ coli,
                                                      const int* __restrict__ scanned,
                                                      unsigned int* __restrict__ ebuf,
                                                      int e, int nbkt, int cpw) {
    __shared__ int cur[512];
    int w = blockIdx.x, tid = threadIdx.x;
    for (int b = tid; b < nbkt; b += 256) cur[b] = scanned[b * NWG + w];
    __syncthreads();
    int i1 = min((w + 1) * cpw, e);
    for (int i = w * cpw + tid; i < i1; i += 256) {
        int c = coli[i];
        int b = c >> 8;
        int p = atomicAdd(&cur[b], 1);
        ebuf[p] = ((unsigned int)rowi[i] << 8) | (unsigned int)(c & 255);
    }
}

// ---------------- phase B: per-bucket local CSR ----------------
__global__ __launch_bounds__(256) void csr_bucket(const int* __restrict__ scanned,
                                                  const unsigned int* __restrict__ ebuf,
                                                  int* __restrict__ row_ptr,
                                                  int* __restrict__ srcs,
                                                  int e, int n, int nbkt) {
    __shared__ int cnt[256], s[256], cur[256];
    int b = blockIdx.x, tid = threadIdx.x;
    int S = scanned[b * NWG];
    int Send = (b == nbkt - 1) ? e : scanned[(b + 1) * NWG];
    cnt[tid] = 0;
    __syncthreads();
    for (int i = S + tid; i < Send; i += 256)
        atomicAdd(&cnt[ebuf[i] & 255], 1);
    __syncthreads();
    int v = cnt[tid];
    s[tid] = v;
    __syncthreads();
    #pragma unroll
    for (int off = 1; off < 256; off <<= 1) {
        int add = (tid >= off) ? s[tid - off] : 0;
        __syncthreads();
        s[tid] += add;
        __syncthreads();
    }
    int offx = s[tid] - v;
    int node = b * 256 + tid;
    if (node < n) row_ptr[node] = S + offx;
    cur[tid] = offx;
    __syncthreads();
    for (int i = S + tid; i < Send; i += 256) {
        unsigned int pe = ebuf[i];
        int lc = (int)(pe & 255u);
        int p = S + atomicAdd(&cur[lc], 1);
        srcs[p] = (int)(pe >> 8);
    }
}

// ---------------- mean aggregation: 16 rows in flight per wave ----------------
__global__ __launch_bounds__(256) void aggregate_mean(
    const float* __restrict__ x, float* __restrict__ mean,
    const int* __restrict__ row_ptr, const int* __restrict__ srcs, int n) {
    int node = blockIdx.x * 4 + (threadIdx.x >> 6);
    if (node >= n) return;
    int lane = threadIdx.x & 63;
    int half = lane >> 5;
    int l32 = lane & 31;
    int beg = row_ptr[node];
    int end = row_ptr[node + 1];

    float4 ac[8];
    #pragma unroll
    for (int k = 0; k < 8; ++k) ac[k] = make_float4(0.f, 0.f, 0.f, 0.f);

    int j = beg;
    for (; j + 16 <= end; j += 16) {
        int sr[8];
        #pragma unroll
        for (int k = 0; k < 8; ++k) sr[k] = srcs[j + 2 * k + half];
        float4 v[8];
        #pragma unroll
        for (int k = 0; k < 8; ++k)
            v[k] = *reinterpret_cast<const float4*>(x + (size_t)sr[k] * D + l32 * 4);
        #pragma unroll
        for (int k = 0; k < 8; ++k) {
            ac[k].x += v[k].x; ac[k].y += v[k].y; ac[k].z += v[k].z; ac[k].w += v[k].w;
        }
    }
    if (j + 8 <= end) {
        int sr[4];
        #pragma unroll
        for (int k = 0; k < 4; ++k) sr[k] = srcs[j + 2 * k + half];
        float4 v[4];
        #pragma unroll
        for (int k = 0; k < 4; ++k)
            v[k] = *reinterpret_cast<const float4*>(x + (size_t)sr[k] * D + l32 * 4);
        #pragma unroll
        for (int k = 0; k < 4; ++k) {
            ac[k].x += v[k].x; ac[k].y += v[k].y; ac[k].z += v[k].z; ac[k].w += v[k].w;
        }
        j += 8;
    }
    if (j + 4 <= end) {
        int s0 = srcs[j + half];
        int s1 = srcs[j + 2 + half];
        float4 v0 = *reinterpret_cast<const float4*>(x + (size_t)s0 * D + l32 * 4);
        float4 v1 = *reinterpret_cast<const float4*>(x + (size_t)s1 * D + l32 * 4);
        ac[0].x += v0.x; ac[0].y += v0.y; ac[0].z += v0.z; ac[0].w += v0.w;
        ac[1].x += v1.x; ac[1].y += v1.y; ac[1].z += v1.z; ac[1].w += v1.w;
        j += 4;
    }
    if (j + 2 <= end) {
        int s0 = srcs[j + half];
        float4 v0 = *reinterpret_cast<const float4*>(x + (size_t)s0 * D + l32 * 4);
        ac[0].x += v0.x; ac[0].y += v0.y; ac[0].z += v0.z; ac[0].w += v0.w;
        j += 2;
    }
    if (j < end && half == 0) {
        int s0 = srcs[j];
        float4 v0 = *reinterpret_cast<const float4*>(x + (size_t)s0 * D + l32 * 4);
        ac[0].x += v0.x; ac[0].y += v0.y; ac[0].z += v0.z; ac[0].w += v0.w;
    }
    // reduce 8 chains -> 1
    #pragma unroll
    for (int k = 4; k >= 1; k >>= 1)
        #pragma unroll
        for (int m = 0; m < k; ++m) {
            ac[m].x += ac[m + k].x; ac[m].y += ac[m + k].y;
            ac[m].z += ac[m + k].z; ac[m].w += ac[m + k].w;
        }
    ac[0].x += __shfl_xor(ac[0].x, 32, 64);
    ac[0].y += __shfl_xor(ac[0].y, 32, 64);
    ac[0].z += __shfl_xor(ac[0].z, 32, 64);
    ac[0].w += __shfl_xor(ac[0].w, 32, 64);

    if (half == 0) {
        float inv = 1.0f / fmaxf((float)(end - beg), 1.0f);
        float4 o;
        o.x = ac[0].x * inv; o.y = ac[0].y * inv; o.z = ac[0].z * inv; o.w = ac[0].w * inv;
        *reinterpret_cast<float4*>(mean + (size_t)node * D + l32 * 4) = o;
    }
}

// ---------------- weight prep: split + transpose ----------------
__global__ __launch_bounds__(256) void split_w(const float* __restrict__ w1l,
                                               const float* __restrict__ w1r,
                                               const float* __restrict__ w2l,
                                               const float* __restrict__ w2r,
                                               short* __restrict__ wt) {
    int b = blockIdx.x;           // 0..255 = layer*128 + n
    int layer = b >> 7;
    int nn = b & 127;
    int k = threadIdx.x;          // 0..255
    const float* wl = layer ? w2l : w1l;
    const float* wr = layer ? w2r : w1r;
    float v = (k < 128) ? wl[k * D + nn] : wr[(k - 128) * D + nn];
    unsigned short h = f2bf_rne(v);
    float lo = v - bf2f(h);
    unsigned short l = f2bf_rne(lo);
    short* base = wt + layer * 65536;
    base[nn * 256 + k] = (short)h;
    base[32768 + nn * 256 + k] = (short)l;
}

// ---------------- MFMA dual-GEMM + bias + relu ----------------
__global__ __launch_bounds__(256, 2) void sage_mm_mfma(
    const float* __restrict__ mean, const float* __restrict__ xin,
    const short* __restrict__ wth, const short* __restrict__ wtl,
    const float* __restrict__ bias, float* __restrict__ out, int n) {
    __shared__ short sAh[128 * 40];
    __shared__ short sAl[128 * 40];
    __shared__ short sBh[128 * 40];
    __shared__ short sBl[128 * 40];
    const int tid = threadIdx.x;
    const int wave = tid >> 6;
    const int lane = tid & 63;
    const int l15 = lane & 15;
    const int kg = lane >> 4;
    const int row0 = blockIdx.x * BM;

    f32x4 acc[2][8];
    #pragma unroll
    for (int fr = 0; fr < 2; ++fr)
        #pragma unroll
        for (int fc = 0; fc < 8; ++fc)
            acc[fr][fc] = (f32x4){0.f, 0.f, 0.f, 0.f};

    float4 pa[4];
    int4 pbh[2], pbl[2];

    #pragma unroll
    for (int i = 0; i < 4; ++i) {
        int f = tid + i * 256;
        int row = f >> 3, k4 = f & 7;
        int gr = row0 + row;
        pa[i] = (gr < n) ? *reinterpret_cast<const float4*>(&mean[(size_t)gr * D + k4 * 4])
                         : make_float4(0.f, 0.f, 0.f, 0.f);
    }
    #pragma unroll
    for (int i = 0; i < 2; ++i) {
        int f = tid + i * 256;
        int n_ = f >> 2, kq = f & 3;
        pbh[i] = *reinterpret_cast<const int4*>(&wth[n_ * 256 + kq * 8]);
        pbl[i] = *reinterpret_cast<const int4*>(&wtl[n_ * 256 + kq * 8]);
    }

    for (int c = 0; c < 8; ++c) {
        #pragma unroll
        for (int i = 0; i < 4; ++i) {
            int f = tid + i * 256;
            int row = f >> 3, k4 = f & 7;
            const float* pv = &pa[i].x;
            unsigned short h[4], l[4];
            #pragma unroll
            for (int j = 0; j < 4; ++j) {
                float v = pv[j];
                h[j] = f2bf_rne(v);
                l[j] = f2bf_rne(v - bf2f(h[j]));
            }
            short* dsth = &sAh[row * 40 + k4 * 4];
            short* dstl = &sAl[row * 40 + k4 * 4];
            #pragma unroll
            for (int j = 0; j < 4; ++j) { dsth[j] = (short)h[j]; dstl[j] = (short)l[j]; }
        }
        #pragma unroll
        for (int i = 0; i < 2; ++i) {
            int f = tid + i * 256;
            int n_ = f >> 2, kq = f & 3;
            *reinterpret_cast<int4*>(&sBh[n_ * 40 + kq * 8]) = pbh[i];
            *reinterpret_cast<int4*>(&sBl[n_ * 40 + kq * 8]) = pbl[i];
        }
        __syncthreads();

        if (c < 7) {
            const float* __restrict__ anext = (c + 1 < 4) ? mean : xin;
            const int ka = ((c + 1) & 3) * 32;
            const int kb = (c + 1) * 32;
            #pragma unroll
            for (int i = 0; i < 4; ++i) {
                int f = tid + i * 256;
                int row = f >> 3, k4 = f & 7;
                int gr = row0 + row;
                pa[i] = (gr < n) ? *reinterpret_cast<const float4*>(&anext[(size_t)gr * D + ka + k4 * 4])
                                 : make_float4(0.f, 0.f, 0.f, 0.f);
            }
            #pragma unroll
            for (int i = 0; i < 2; ++i) {
                int f = tid + i * 256;
                int n_ = f >> 2, kq = f & 3;
                pbh[i] = *reinterpret_cast<const int4*>(&wth[n_ * 256 + kb + kq * 8]);
                pbl[i] = *reinterpret_cast<const int4*>(&wtl[n_ * 256 + kb + kq * 8]);
            }
        }

        short8 ah[2], al[2];
        #pragma unroll
        for (int fr = 0; fr < 2; ++fr) {
            int r = wave * 32 + fr * 16 + l15;
            ah[fr] = *reinterpret_cast<const short8*>(&sAh[r * 40 + kg * 8]);
            al[fr] = *reinterpret_cast<const short8*>(&sAl[r * 40 + kg * 8]);
        }
        #pragma unroll
        for (int fc = 0; fc < 8; ++fc) {
            int cc = fc * 16 + l15;
            short8 bh = *reinterpret_cast<const short8*>(&sBh[cc * 40 + kg * 8]);
            short8 bl = *reinterpret_cast<const short8*>(&sBl[cc * 40 + kg * 8]);
            #pragma unroll
            for (int fr = 0; fr < 2; ++fr) {
                acc[fr][fc] = __builtin_amdgcn_mfma_f32_16x16x32_bf16(ah[fr], bh, acc[fr][fc], 0, 0, 0);
                acc[fr][fc] = __builtin_amdgcn_mfma_f32_16x16x32_bf16(al[fr], bh, acc[fr][fc], 0, 0, 0);
                acc[fr][fc] = __builtin_amdgcn_mfma_f32_16x16x32_bf16(ah[fr], bl, acc[fr][fc], 0, 0, 0);
            }
        }
        __syncthreads();
    }

    float bz[8];
    #pragma unroll
    for (int fc = 0; fc < 8; ++fc) bz[fc] = bias[fc * 16 + l15];
    #pragma unroll
    for (int fr = 0; fr < 2; ++fr) {
        #pragma unroll
        for (int j = 0; j < 4; ++j) {
            int gr = row0 + wave * 32 + fr * 16 + kg * 4 + j;
            if (gr < n) {
                #pragma unroll
                for (int fc = 0; fc < 8; ++fc)
                    out[(size_t)gr * D + fc * 16 + l15] = fmaxf(acc[fr][fc][j] + bz[fc], 0.f);
            }
        }
    }
}

// ---------------- launch ----------------

extern "C" void kernel_launch(void* const* d_in, const int* in_sizes, int n_in,
                              void* d_out, int out_size, void* d_ws, size_t ws_size,
                              hipStream_t stream) {
    const float* x   = (const float*)d_in[0];
    const int*   ei  = (const int*)d_in[1];
    const float* w1l = (const float*)d_in[2];
    const float* b1l = (const float*)d_in[3];
    const float* w1r = (const float*)d_in[4];
    const float* w2l = (const float*)d_in[5];
    const float* b2l = (const float*)d_in[6];
    const float* w2r = (const float*)d_in[7];
    float* out = (float*)d_out;

    const int n = in_sizes[0] / D;   // 100000
    const int e = in_sizes[1] / 2;   // 1600000
    const int* rowi = ei;            // sources
    const int* coli = ei + e;        // targets

    const int nbkt = (n + 255) >> 8;          // 391 (<=512)
    const int n2 = nbkt * NWG;                // 100096
    const int cpw = (e + NWG - 1) / NWG;      // 6250
    const int nb2 = n2 / 256;                 // 391
    const int PN = ((n + 1 + 63) / 64) * 64;

    int* row_ptr  = (int*)d_ws;               // PN
    int* hist_t   = row_ptr + PN;             // n2
    int* scanned  = hist_t + n2;              // n2
    int* bsum     = scanned + n2;             // 512
    int* srcs     = bsum + 512;               // e
    short* wt     = (short*)(srcs + e);       // 4 * 32768 shorts (256KB)
    float* mean   = (float*)(wt + 4 * 32768); // n*D floats
    unsigned int* ebuf = (unsigned int*)mean; // e (aliased; dead before agg)

    split_w<<<256, 256, 0, stream>>>(w1l, w1r, w2l, w2r, wt);

    hist_bucket<<<NWG, 256, 0, stream>>>(coli, hist_t, e, nbkt, cpw);
    scan1<<<nb2, 256, 0, stream>>>(hist_t, scanned, bsum, n2);
    scan2<<<1, 512, 0, stream>>>(bsum, nb2);
    scan3b<<<nb2, 256, 0, stream>>>(scanned, bsum, n2);
    scatter_bucket<<<NWG, 256, 0, stream>>>(rowi, coli, scanned, ebuf, e, nbkt, cpw);
    csr_bucket<<<nbkt, 256, 0, stream>>>(scanned, ebuf, row_ptr, srcs, e, n, nbkt);
    set_end<<<1, 1, 0, stream>>>(row_ptr, n, e);

    const int mm_grid = (n + BM - 1) / BM;

    // layer 1: h = relu(mean(x)@w1l + b1l + x@w1r), h in d_out
    aggregate_mean<<<(n + 3) / 4, 256, 0, stream>>>(x, mean, row_ptr, srcs, n);
    sage_mm_mfma<<<mm_grid, 256, 0, stream>>>(mean, x, wt, wt + 32768, b1l, out, n);

    // layer 2: out = relu(mean(h)@w2l + b2l + h@w2r), in place over h
    aggregate_mean<<<(n + 3) / 4, 256, 0, stream>>>(out, mean, row_ptr, srcs, n);
    sage_mm_mfma<<<mm_grid, 256, 0, stream>>>(mean, out, wt + 65536, wt + 98304, b2l, out, n);
}

// Round 9
// 442.140 us; speedup vs baseline: 2.0517x; 1.1418x over previous
//
#include <hip/hip_runtime.h>

#define D 128
#define BM 128
#define NWG 256  // workgroups in hist/scatter phases

typedef short short8 __attribute__((ext_vector_type(8)));
typedef float f32x4 __attribute__((ext_vector_type(4)));

__device__ inline unsigned short f2bf_rne(float x) {
    unsigned int b = __float_as_uint(x);
    unsigned int r = (b + 0x7FFFu + ((b >> 16) & 1u)) >> 16;
    return (unsigned short)r;
}
__device__ inline float bf2f(unsigned short h) {
    return __uint_as_float(((unsigned int)h) << 16);
}
__device__ inline void acc_bf(float4& a, ushort4 u) {
    a.x += __uint_as_float((unsigned int)u.x << 16);
    a.y += __uint_as_float((unsigned int)u.y << 16);
    a.z += __uint_as_float((unsigned int)u.z << 16);
    a.w += __uint_as_float((unsigned int)u.w << 16);
}

// ---------------- x -> bf16 plane ----------------
__global__ __launch_bounds__(256) void convert_x(const float* __restrict__ x,
                                                 unsigned short* __restrict__ xb,
                                                 int total) {
    int i = (blockIdx.x * 256 + threadIdx.x) * 8;
    if (i < total) {
        float4 a = *reinterpret_cast<const float4*>(x + i);
        float4 b = *reinterpret_cast<const float4*>(x + i + 4);
        ushort4 u0, u1;
        u0.x = f2bf_rne(a.x); u0.y = f2bf_rne(a.y); u0.z = f2bf_rne(a.z); u0.w = f2bf_rne(a.w);
        u1.x = f2bf_rne(b.x); u1.y = f2bf_rne(b.y); u1.z = f2bf_rne(b.z); u1.w = f2bf_rne(b.w);
        *reinterpret_cast<ushort4*>(xb + i) = u0;
        *reinterpret_cast<ushort4*>(xb + i + 4) = u1;
    }
}

// ---------------- generic scan (256/block) ----------------

__global__ void scan1(const int* __restrict__ in, int* __restrict__ out,
                      int* __restrict__ bsum, int n) {
    __shared__ int s[256];
    int t = threadIdx.x;
    int i = blockIdx.x * 256 + t;
    int v = (i < n) ? in[i] : 0;
    s[t] = v;
    __syncthreads();
    #pragma unroll
    for (int off = 1; off < 256; off <<= 1) {
        int add = (t >= off) ? s[t - off] : 0;
        __syncthreads();
        s[t] += add;
        __syncthreads();
    }
    if (i < n) out[i] = s[t] - v;
    if (t == 255) bsum[blockIdx.x] = s[255];
}

__global__ void scan2(int* __restrict__ bsum, int nb) {
    __shared__ int s[512];
    int t = threadIdx.x;
    int v = (t < nb) ? bsum[t] : 0;
    s[t] = v;
    __syncthreads();
    #pragma unroll
    for (int off = 1; off < 512; off <<= 1) {
        int add = (t >= off) ? s[t - off] : 0;
        __syncthreads();
        s[t] += add;
        __syncthreads();
    }
    if (t < nb) bsum[t] = s[t] - v;
}

__global__ void scan3b(int* __restrict__ out, const int* __restrict__ bsum, int n) {
    int i = blockIdx.x * blockDim.x + threadIdx.x;
    if (i < n) out[i] += bsum[i >> 8];
}

__global__ void set_end(int* __restrict__ row_ptr, int n, int e) {
    row_ptr[n] = e;
}

// ---------------- phase A: bucket histogram + scatter ----------------

__global__ __launch_bounds__(256) void hist_bucket(const int* __restrict__ coli,
                                                   int* __restrict__ hist_t,
                                                   int e, int nbkt, int cpw) {
    __shared__ int hist[512];
    int w = blockIdx.x, tid = threadIdx.x;
    for (int b = tid; b < nbkt; b += 256) hist[b] = 0;
    __syncthreads();
    int i1 = min((w + 1) * cpw, e);
    for (int i = w * cpw + tid; i < i1; i += 256)
        atomicAdd(&hist[coli[i] >> 8], 1);
    __syncthreads();
    for (int b = tid; b < nbkt; b += 256) hist_t[b * NWG + w] = hist[b];
}

__global__ __launch_bounds__(256) void scatter_bucket(const int* __restrict__ rowi,
                                                      const int* __restrict__ coli,
                                                      const int* __restrict__ scanned,
                                                      unsigned int* __restrict__ ebuf,
                                                      int e, int nbkt, int cpw) {
    __shared__ int cur[512];
    int w = blockIdx.x, tid = threadIdx.x;
    for (int b = tid; b < nbkt; b += 256) cur[b] = scanned[b * NWG + w];
    __syncthreads();
    int i1 = min((w + 1) * cpw, e);
    for (int i = w * cpw + tid; i < i1; i += 256) {
        int c = coli[i];
        int b = c >> 8;
        int p = atomicAdd(&cur[b], 1);
        ebuf[p] = ((unsigned int)rowi[i] << 8) | (unsigned int)(c & 255);
    }
}

// ---------------- phase B: per-bucket local CSR ----------------
__global__ __launch_bounds__(256) void csr_bucket(const int* __restrict__ scanned,
                                                  const unsigned int* __restrict__ ebuf,
                                                  int* __restrict__ row_ptr,
                                                  int* __restrict__ srcs,
                                                  int e, int n, int nbkt) {
    __shared__ int cnt[256], s[256], cur[256];
    int b = blockIdx.x, tid = threadIdx.x;
    int S = scanned[b * NWG];
    int Send = (b == nbkt - 1) ? e : scanned[(b + 1) * NWG];
    cnt[tid] = 0;
    __syncthreads();
    for (int i = S + tid; i < Send; i += 256)
        atomicAdd(&cnt[ebuf[i] & 255], 1);
    __syncthreads();
    int v = cnt[tid];
    s[tid] = v;
    __syncthreads();
    #pragma unroll
    for (int off = 1; off < 256; off <<= 1) {
        int add = (tid >= off) ? s[tid - off] : 0;
        __syncthreads();
        s[tid] += add;
        __syncthreads();
    }
    int offx = s[tid] - v;
    int node = b * 256 + tid;
    if (node < n) row_ptr[node] = S + offx;
    cur[tid] = offx;
    __syncthreads();
    for (int i = S + tid; i < Send; i += 256) {
        unsigned int pe = ebuf[i];
        int lc = (int)(pe & 255u);
        int p = S + atomicAdd(&cur[lc], 1);
        srcs[p] = (int)(pe >> 8);
    }
}

// ---------------- mean aggregation over bf16 rows (256B/row) ----------------
// one wave per node; 32 lanes x ushort4 (8B) = 256B row; 16 rows in flight.
__global__ __launch_bounds__(256) void aggregate_mean_bf16(
    const unsigned short* __restrict__ xb, float* __restrict__ mean,
    const int* __restrict__ row_ptr, const int* __restrict__ srcs, int n) {
    int node = blockIdx.x * 4 + (threadIdx.x >> 6);
    if (node >= n) return;
    int lane = threadIdx.x & 63;
    int half = lane >> 5;
    int l32 = lane & 31;
    int beg = row_ptr[node];
    int end = row_ptr[node + 1];

    float4 ac[8];
    #pragma unroll
    for (int k = 0; k < 8; ++k) ac[k] = make_float4(0.f, 0.f, 0.f, 0.f);

    int j = beg;
    for (; j + 16 <= end; j += 16) {
        int sr[8];
        #pragma unroll
        for (int k = 0; k < 8; ++k) sr[k] = srcs[j + 2 * k + half];
        ushort4 v[8];
        #pragma unroll
        for (int k = 0; k < 8; ++k)
            v[k] = *reinterpret_cast<const ushort4*>(xb + (size_t)sr[k] * D + l32 * 4);
        #pragma unroll
        for (int k = 0; k < 8; ++k) acc_bf(ac[k], v[k]);
    }
    if (j + 8 <= end) {
        int sr[4];
        #pragma unroll
        for (int k = 0; k < 4; ++k) sr[k] = srcs[j + 2 * k + half];
        ushort4 v[4];
        #pragma unroll
        for (int k = 0; k < 4; ++k)
            v[k] = *reinterpret_cast<const ushort4*>(xb + (size_t)sr[k] * D + l32 * 4);
        #pragma unroll
        for (int k = 0; k < 4; ++k) acc_bf(ac[k], v[k]);
        j += 8;
    }
    if (j + 4 <= end) {
        ushort4 v0 = *reinterpret_cast<const ushort4*>(xb + (size_t)srcs[j + half] * D + l32 * 4);
        ushort4 v1 = *reinterpret_cast<const ushort4*>(xb + (size_t)srcs[j + 2 + half] * D + l32 * 4);
        acc_bf(ac[0], v0);
        acc_bf(ac[1], v1);
        j += 4;
    }
    if (j + 2 <= end) {
        ushort4 v0 = *reinterpret_cast<const ushort4*>(xb + (size_t)srcs[j + half] * D + l32 * 4);
        acc_bf(ac[0], v0);
        j += 2;
    }
    if (j < end && half == 0) {
        ushort4 v0 = *reinterpret_cast<const ushort4*>(xb + (size_t)srcs[j] * D + l32 * 4);
        acc_bf(ac[0], v0);
    }
    // reduce 8 chains -> 1
    #pragma unroll
    for (int k = 4; k >= 1; k >>= 1)
        #pragma unroll
        for (int m = 0; m < k; ++m) {
            ac[m].x += ac[m + k].x; ac[m].y += ac[m + k].y;
            ac[m].z += ac[m + k].z; ac[m].w += ac[m + k].w;
        }
    ac[0].x += __shfl_xor(ac[0].x, 32, 64);
    ac[0].y += __shfl_xor(ac[0].y, 32, 64);
    ac[0].z += __shfl_xor(ac[0].z, 32, 64);
    ac[0].w += __shfl_xor(ac[0].w, 32, 64);

    if (half == 0) {
        float inv = 1.0f / fmaxf((float)(end - beg), 1.0f);
        float4 o;
        o.x = ac[0].x * inv; o.y = ac[0].y * inv; o.z = ac[0].z * inv; o.w = ac[0].w * inv;
        *reinterpret_cast<float4*>(mean + (size_t)node * D + l32 * 4) = o;
    }
}

// ---------------- weight prep: split + transpose ----------------
__global__ __launch_bounds__(256) void split_w(const float* __restrict__ w1l,
                                               const float* __restrict__ w1r,
                                               const float* __restrict__ w2l,
                                               const float* __restrict__ w2r,
                                               short* __restrict__ wt) {
    int b = blockIdx.x;           // 0..255 = layer*128 + n
    int layer = b >> 7;
    int nn = b & 127;
    int k = threadIdx.x;          // 0..255
    const float* wl = layer ? w2l : w1l;
    const float* wr = layer ? w2r : w1r;
    float v = (k < 128) ? wl[k * D + nn] : wr[(k - 128) * D + nn];
    unsigned short h = f2bf_rne(v);
    float lo = v - bf2f(h);
    unsigned short l = f2bf_rne(lo);
    short* base = wt + layer * 65536;
    base[nn * 256 + k] = (short)h;
    base[32768 + nn * 256 + k] = (short)l;
}

// ---------------- MFMA dual-GEMM + bias + relu ----------------
// hbout != nullptr: also write relu(h) as bf16 plane (for next layer's gather)
__global__ __launch_bounds__(256, 2) void sage_mm_mfma(
    const float* __restrict__ mean, const float* __restrict__ xin,
    const short* __restrict__ wth, const short* __restrict__ wtl,
    const float* __restrict__ bias, float* __restrict__ out,
    unsigned short* __restrict__ hbout, int n) {
    __shared__ short sAh[128 * 40];
    __shared__ short sAl[128 * 40];
    __shared__ short sBh[128 * 40];
    __shared__ short sBl[128 * 40];
    const int tid = threadIdx.x;
    const int wave = tid >> 6;
    const int lane = tid & 63;
    const int l15 = lane & 15;
    const int kg = lane >> 4;
    const int row0 = blockIdx.x * BM;

    f32x4 acc[2][8];
    #pragma unroll
    for (int fr = 0; fr < 2; ++fr)
        #pragma unroll
        for (int fc = 0; fc < 8; ++fc)
            acc[fr][fc] = (f32x4){0.f, 0.f, 0.f, 0.f};

    float4 pa[4];
    int4 pbh[2], pbl[2];

    #pragma unroll
    for (int i = 0; i < 4; ++i) {
        int f = tid + i * 256;
        int row = f >> 3, k4 = f & 7;
        int gr = row0 + row;
        pa[i] = (gr < n) ? *reinterpret_cast<const float4*>(&mean[(size_t)gr * D + k4 * 4])
                         : make_float4(0.f, 0.f, 0.f, 0.f);
    }
    #pragma unroll
    for (int i = 0; i < 2; ++i) {
        int f = tid + i * 256;
        int n_ = f >> 2, kq = f & 3;
        pbh[i] = *reinterpret_cast<const int4*>(&wth[n_ * 256 + kq * 8]);
        pbl[i] = *reinterpret_cast<const int4*>(&wtl[n_ * 256 + kq * 8]);
    }

    for (int c = 0; c < 8; ++c) {
        #pragma unroll
        for (int i = 0; i < 4; ++i) {
            int f = tid + i * 256;
            int row = f >> 3, k4 = f & 7;
            const float* pv = &pa[i].x;
            unsigned short h[4], l[4];
            #pragma unroll
            for (int j = 0; j < 4; ++j) {
                float v = pv[j];
                h[j] = f2bf_rne(v);
                l[j] = f2bf_rne(v - bf2f(h[j]));
            }
            short* dsth = &sAh[row * 40 + k4 * 4];
            short* dstl = &sAl[row * 40 + k4 * 4];
            #pragma unroll
            for (int j = 0; j < 4; ++j) { dsth[j] = (short)h[j]; dstl[j] = (short)l[j]; }
        }
        #pragma unroll
        for (int i = 0; i < 2; ++i) {
            int f = tid + i * 256;
            int n_ = f >> 2, kq = f & 3;
            *reinterpret_cast<int4*>(&sBh[n_ * 40 + kq * 8]) = pbh[i];
            *reinterpret_cast<int4*>(&sBl[n_ * 40 + kq * 8]) = pbl[i];
        }
        __syncthreads();

        if (c < 7) {
            const float* __restrict__ anext = (c + 1 < 4) ? mean : xin;
            const int ka = ((c + 1) & 3) * 32;
            const int kb = (c + 1) * 32;
            #pragma unroll
            for (int i = 0; i < 4; ++i) {
                int f = tid + i * 256;
                int row = f >> 3, k4 = f & 7;
                int gr = row0 + row;
                pa[i] = (gr < n) ? *reinterpret_cast<const float4*>(&anext[(size_t)gr * D + ka + k4 * 4])
                                 : make_float4(0.f, 0.f, 0.f, 0.f);
            }
            #pragma unroll
            for (int i = 0; i < 2; ++i) {
                int f = tid + i * 256;
                int n_ = f >> 2, kq = f & 3;
                pbh[i] = *reinterpret_cast<const int4*>(&wth[n_ * 256 + kb + kq * 8]);
                pbl[i] = *reinterpret_cast<const int4*>(&wtl[n_ * 256 + kb + kq * 8]);
            }
        }

        short8 ah[2], al[2];
        #pragma unroll
        for (int fr = 0; fr < 2; ++fr) {
            int r = wave * 32 + fr * 16 + l15;
            ah[fr] = *reinterpret_cast<const short8*>(&sAh[r * 40 + kg * 8]);
            al[fr] = *reinterpret_cast<const short8*>(&sAl[r * 40 + kg * 8]);
        }
        #pragma unroll
        for (int fc = 0; fc < 8; ++fc) {
            int cc = fc * 16 + l15;
            short8 bh = *reinterpret_cast<const short8*>(&sBh[cc * 40 + kg * 8]);
            short8 bl = *reinterpret_cast<const short8*>(&sBl[cc * 40 + kg * 8]);
            #pragma unroll
            for (int fr = 0; fr < 2; ++fr) {
                acc[fr][fc] = __builtin_amdgcn_mfma_f32_16x16x32_bf16(ah[fr], bh, acc[fr][fc], 0, 0, 0);
                acc[fr][fc] = __builtin_amdgcn_mfma_f32_16x16x32_bf16(al[fr], bh, acc[fr][fc], 0, 0, 0);
                acc[fr][fc] = __builtin_amdgcn_mfma_f32_16x16x32_bf16(ah[fr], bl, acc[fr][fc], 0, 0, 0);
            }
        }
        __syncthreads();
    }

    float bz[8];
    #pragma unroll
    for (int fc = 0; fc < 8; ++fc) bz[fc] = bias[fc * 16 + l15];
    #pragma unroll
    for (int fr = 0; fr < 2; ++fr) {
        #pragma unroll
        for (int j = 0; j < 4; ++j) {
            int gr = row0 + wave * 32 + fr * 16 + kg * 4 + j;
            if (gr < n) {
                #pragma unroll
                for (int fc = 0; fc < 8; ++fc) {
                    float v = fmaxf(acc[fr][fc][j] + bz[fc], 0.f);
                    out[(size_t)gr * D + fc * 16 + l15] = v;
                    if (hbout) hbout[(size_t)gr * D + fc * 16 + l15] = f2bf_rne(v);
                }
            }
        }
    }
}

// ---------------- launch ----------------

extern "C" void kernel_launch(void* const* d_in, const int* in_sizes, int n_in,
                              void* d_out, int out_size, void* d_ws, size_t ws_size,
                              hipStream_t stream) {
    const float* x   = (const float*)d_in[0];
    const int*   ei  = (const int*)d_in[1];
    const float* w1l = (const float*)d_in[2];
    const float* b1l = (const float*)d_in[3];
    const float* w1r = (const float*)d_in[4];
    const float* w2l = (const float*)d_in[5];
    const float* b2l = (const float*)d_in[6];
    const float* w2r = (const float*)d_in[7];
    float* out = (float*)d_out;

    const int n = in_sizes[0] / D;   // 100000
    const int e = in_sizes[1] / 2;   // 1600000
    const int* rowi = ei;            // sources
    const int* coli = ei + e;        // targets

    const int nbkt = (n + 255) >> 8;          // 391 (<=512)
    const int n2 = nbkt * NWG;                // 100096
    const int cpw = (e + NWG - 1) / NWG;      // 6250
    const int nb2 = n2 / 256;                 // 391
    const int PN = ((n + 1 + 63) / 64) * 64;
    const int total = n * D;                  // 12,800,000

    int* row_ptr  = (int*)d_ws;               // PN
    int* hist_t   = row_ptr + PN;             // n2
    int* scanned  = hist_t + n2;              // n2
    int* bsum     = scanned + n2;             // 512
    int* srcs     = bsum + 512;               // e
    short* wt     = (short*)(srcs + e);       // 4 * 32768 shorts (256KB)
    float* mean   = (float*)(wt + 4 * 32768); // n*D floats
    unsigned short* xhb = (unsigned short*)(mean + (size_t)total); // n*D bf16
    unsigned int* ebuf  = (unsigned int*)mean; // e (aliased; dead before agg)

    // x -> bf16 plane (xhb); also reused for h after layer-1 mm
    convert_x<<<(total / 8 + 255) / 256, 256, 0, stream>>>(x, xhb, total);
    split_w<<<256, 256, 0, stream>>>(w1l, w1r, w2l, w2r, wt);

    hist_bucket<<<NWG, 256, 0, stream>>>(coli, hist_t, e, nbkt, cpw);
    scan1<<<nb2, 256, 0, stream>>>(hist_t, scanned, bsum, n2);
    scan2<<<1, 512, 0, stream>>>(bsum, nb2);
    scan3b<<<nb2, 256, 0, stream>>>(scanned, bsum, n2);
    scatter_bucket<<<NWG, 256, 0, stream>>>(rowi, coli, scanned, ebuf, e, nbkt, cpw);
    csr_bucket<<<nbkt, 256, 0, stream>>>(scanned, ebuf, row_ptr, srcs, e, n, nbkt);
    set_end<<<1, 1, 0, stream>>>(row_ptr, n, e);

    const int mm_grid = (n + BM - 1) / BM;

    // layer 1: h = relu(mean(x)@w1l + b1l + x@w1r); h fp32 in d_out, bf16 in xhb
    aggregate_mean_bf16<<<(n + 3) / 4, 256, 0, stream>>>(xhb, mean, row_ptr, srcs, n);
    sage_mm_mfma<<<mm_grid, 256, 0, stream>>>(mean, x, wt, wt + 32768, b1l, out, xhb, n);

    // layer 2: out = relu(mean(h)@w2l + b2l + h@w2r), in place over h
    aggregate_mean_bf16<<<(n + 3) / 4, 256, 0, stream>>>(xhb, mean, row_ptr, srcs, n);
    sage_mm_mfma<<<mm_grid, 256, 0, stream>>>(mean, out, wt + 65536, wt + 98304, b2l, out, nullptr, n);
}